// Round 1
// baseline (726.106 us; speedup 1.0000x reference)
//
#include <hip/hip_runtime.h>

// ---------------------------------------------------------------------------
// Self-attention, B=4 S=4096 D=DOUT=1024, fp32 in/out.
// Reformulation: scores = x (Wq Wk^T / 32) x^T  -> t = x*M ; S = t x^T
//   (keeps Q-path error ~30x smaller than naive bf16 q,k projections)
// Pipeline:
//   1. cast x -> bf16
//   2. prep weights: Wk bf16, Wq bf16 (pre-scaled 1/32), Wv^T bf16
//   3. Mt = Wk * Wq_s^T        (1024x1024x1024, bf16 MFMA)
//   4. t  = x * Mt^T           (16384x1024x1024)
//   5. vT[b] = WvT * x_b^T     (4 x [1024x4096x1024])
//   per batch b (chunked by CR query rows):
//   6. S = t_b * x_b^T         (fp32 out, CRx4096x1024)
//   7. row softmax, write P bf16 in-place over S
//   8. out_b = P * vT_b^T      (fp32 out, CRx1024x4096)
// ---------------------------------------------------------------------------

typedef unsigned short ushort_t;
typedef __attribute__((ext_vector_type(8))) short     bf16x8;
typedef __attribute__((ext_vector_type(4))) float     f32x4;
typedef __attribute__((ext_vector_type(4))) unsigned int u32x4;
typedef __attribute__((ext_vector_type(4))) unsigned short u16x4;

__device__ __forceinline__ unsigned short f2bf(float f) {
  unsigned u = __float_as_uint(f);
  return (unsigned short)((u + 0x7FFFu + ((u >> 16) & 1u)) >> 16);
}

// async global -> LDS, 16 bytes per lane
#define GLOAD16(gsrc, ldst)                                                        \
  __builtin_amdgcn_global_load_lds(                                                \
      (const __attribute__((address_space(1))) void*)(gsrc),                       \
      (__attribute__((address_space(3))) void*)(ldst), 16, 0, 0)

// ---------------------------------------------------------------------------
// cast fp32 -> bf16, 8 elements per thread
__global__ __launch_bounds__(256) void cast_bf16_kernel(const float* __restrict__ in,
                                                        ushort_t* __restrict__ out) {
  long i = (long)blockIdx.x * 256 + threadIdx.x;   // one 8-elem chunk each
  const f32x4* p = (const f32x4*)(in + i * 8);
  f32x4 a = p[0], b = p[1];
  u32x4 o;
  o.x = (unsigned)f2bf(a[0]) | ((unsigned)f2bf(a[1]) << 16);
  o.y = (unsigned)f2bf(a[2]) | ((unsigned)f2bf(a[3]) << 16);
  o.z = (unsigned)f2bf(b[0]) | ((unsigned)f2bf(b[1]) << 16);
  o.w = (unsigned)f2bf(b[2]) | ((unsigned)f2bf(b[3]) << 16);
  ((u32x4*)out)[i] = o;
}

// weights: kernel fp32 [3][1024][1024] -> Wk bf16, Wq*(1/32) bf16, Wv^T bf16
__global__ __launch_bounds__(256) void prep_weights_kernel(const float* __restrict__ kern,
                                                           ushort_t* __restrict__ wk,
                                                           ushort_t* __restrict__ wq,
                                                           ushort_t* __restrict__ wvt) {
  int idx = blockIdx.x * 256 + threadIdx.x;          // 0 .. 1048575
  wk[idx] = f2bf(kern[idx]);
  wq[idx] = f2bf(kern[1048576 + idx] * 0.03125f);    // fold 1/sqrt(1024)
  int e = idx >> 10, d = idx & 1023;                 // wvt[e][d] = Wv[d][e]
  wvt[idx] = f2bf(kern[2097152 + d * 1024 + e]);
}

// ---------------------------------------------------------------------------
// GEMM (B^T layout): C[m,n] = sum_k A[m,k]*B[n,k], bf16 in, fp32 accum.
// 128x128 tile, BK=64, 4 waves (each 64x64), mfma 16x16x32 bf16.
// global_load_lds staging with source-side XOR swizzle (conflict-free ds_read_b128).
template <int OUT_BF16>
__global__ __launch_bounds__(256) void gemm_bt(const ushort_t* __restrict__ A, long lda, long batchA,
                                               const ushort_t* __restrict__ B, long ldb, long batchB,
                                               void* __restrict__ C, long ldc, long batchC,
                                               int K) {
  __shared__ ushort_t lA[128 * 64];
  __shared__ ushort_t lB[128 * 64];

  const int tid  = threadIdx.x;
  const int lane = tid & 63;
  const int wid  = tid >> 6;
  const int wr   = wid >> 1;   // wave row 0..1
  const int wc   = wid & 1;    // wave col 0..1

  const ushort_t* Ab = A + (long)blockIdx.z * batchA + (long)blockIdx.y * 128 * lda;
  const ushort_t* Bb = B + (long)blockIdx.z * batchB + (long)blockIdx.x * 128 * ldb;

  f32x4 acc[4][4] = {};

  const int nkt = K >> 6;
  for (int kt = 0; kt < nkt; ++kt) {
#pragma unroll
    for (int i = 0; i < 4; ++i) {            // A tile: 128 rows x 64 cols bf16
      int c = tid + i * 256;                 // 16B chunk id 0..1023
      int row = c >> 3, p = c & 7;
      int sc = p ^ (row & 7);                // source-side swizzle
      GLOAD16(Ab + (long)row * lda + kt * 64 + sc * 8, &lA[c * 8]);
    }
#pragma unroll
    for (int i = 0; i < 4; ++i) {            // B tile
      int c = tid + i * 256;
      int row = c >> 3, p = c & 7;
      int sc = p ^ (row & 7);
      GLOAD16(Bb + (long)row * ldb + kt * 64 + sc * 8, &lB[c * 8]);
    }
    __syncthreads();                         // drains vmcnt -> LDS ready

    const int lr = lane & 15, lg = lane >> 4;
#pragma unroll
    for (int kk = 0; kk < 2; ++kk) {
      bf16x8 af[4], bfr[4];
#pragma unroll
      for (int m = 0; m < 4; ++m) {
        int row = wr * 64 + m * 16 + lr;
        int cidx = kk * 4 + lg;
        af[m] = *(const bf16x8*)((const char*)lA + row * 128 + ((cidx ^ (row & 7)) << 4));
      }
#pragma unroll
      for (int n = 0; n < 4; ++n) {
        int row = wc * 64 + n * 16 + lr;
        int cidx = kk * 4 + lg;
        bfr[n] = *(const bf16x8*)((const char*)lB + row * 128 + ((cidx ^ (row & 7)) << 4));
      }
#pragma unroll
      for (int m = 0; m < 4; ++m)
#pragma unroll
        for (int n = 0; n < 4; ++n)
          acc[m][n] = __builtin_amdgcn_mfma_f32_16x16x32_bf16(af[m], bfr[n], acc[m][n], 0, 0, 0);
    }
    __syncthreads();                         // compute done before next overwrite
  }

  // epilogue: C/D layout col = lane&15, row = (lane>>4)*4 + j
  const long Crow0 = (long)blockIdx.y * 128 + wr * 64;
  const long Ccol0 = (long)blockIdx.x * 128 + wc * 64;
  float*     Cf = (float*)C + (long)blockIdx.z * batchC;
  ushort_t*  Cb = (ushort_t*)C + (long)blockIdx.z * batchC;
#pragma unroll
  for (int m = 0; m < 4; ++m) {
    long r0 = Crow0 + m * 16 + ((lane >> 4) << 2);
#pragma unroll
    for (int n = 0; n < 4; ++n) {
      long cc = Ccol0 + n * 16 + (lane & 15);
#pragma unroll
      for (int j = 0; j < 4; ++j) {
        float val = acc[m][n][j];
        if (OUT_BF16) Cb[(r0 + j) * ldc + cc] = f2bf(val);
        else          Cf[(r0 + j) * ldc + cc] = val;
      }
    }
  }
}

// ---------------------------------------------------------------------------
// row softmax over 4096 fp32 scores; write normalized P bf16 in-place (packed
// at row start). One block (256 thr) per row; whole row in registers first.
__global__ __launch_bounds__(256) void softmax_kernel(float* __restrict__ S) {
  float* row = S + (long)blockIdx.x * 4096;
  const int tid = threadIdx.x;
  __shared__ float red[4];

  f32x4 v[4];
#pragma unroll
  for (int i = 0; i < 4; ++i) v[i] = ((const f32x4*)row)[tid + i * 256];

  float m = -1e30f;
#pragma unroll
  for (int i = 0; i < 4; ++i)
#pragma unroll
    for (int j = 0; j < 4; ++j) m = fmaxf(m, v[i][j]);
  for (int o = 32; o; o >>= 1) m = fmaxf(m, __shfl_xor(m, o));
  if ((tid & 63) == 0) red[tid >> 6] = m;
  __syncthreads();
  m = fmaxf(fmaxf(red[0], red[1]), fmaxf(red[2], red[3]));

  float p[16];
  float s = 0.f;
#pragma unroll
  for (int i = 0; i < 4; ++i)
#pragma unroll
    for (int j = 0; j < 4; ++j) {
      float e = __expf(v[i][j] - m);
      p[i * 4 + j] = e;
      s += e;
    }
  for (int o = 32; o; o >>= 1) s += __shfl_xor(s, o);
  __syncthreads();
  if ((tid & 63) == 0) red[tid >> 6] = s;
  __syncthreads();
  s = red[0] + red[1] + red[2] + red[3];
  float inv = 1.0f / s;

  u16x4* prow = (u16x4*)row;
#pragma unroll
  for (int i = 0; i < 4; ++i) {
    u16x4 o;
    o.x = f2bf(p[i * 4 + 0] * inv);
    o.y = f2bf(p[i * 4 + 1] * inv);
    o.z = f2bf(p[i * 4 + 2] * inv);
    o.w = f2bf(p[i * 4 + 3] * inv);
    prow[tid + i * 256] = o;                 // bytes [8c, 8c+8) of the row
  }
}

// ---------------------------------------------------------------------------
extern "C" void kernel_launch(void* const* d_in, const int* in_sizes, int n_in,
                              void* d_out, int out_size, void* d_ws, size_t ws_size,
                              hipStream_t stream) {
  const float* x    = (const float*)d_in[0];   // [4,4096,1024]
  const float* kern = (const float*)d_in[1];   // [3,1024,1024]
  float* out = (float*)d_out;                  // [4,4096,1024]

  char* p = (char*)d_ws;
  ushort_t* xbf = (ushort_t*)p; p += 33554432;         // 16384x1024 bf16
  ushort_t* t   = (ushort_t*)p; p += 33554432;         // 16384x1024 bf16
  ushort_t* vT  = (ushort_t*)p; p += 33554432;         // 4x1024x4096 bf16
  ushort_t* wk  = (ushort_t*)p; p += 2097152;
  ushort_t* wq  = (ushort_t*)p; p += 2097152;
  ushort_t* wvt = (ushort_t*)p; p += 2097152;
  ushort_t* mt  = (ushort_t*)p; p += 2097152;
  float* Sbuf = (float*)p;
  size_t fixed = (size_t)(p - (char*)d_ws);

  long CR = 4096;                                       // query-chunk rows
  while (CR > 256 && fixed + (size_t)CR * 4096 * 4 > ws_size) CR >>= 1;

  cast_bf16_kernel<<<8192, 256, 0, stream>>>(x, xbf);
  prep_weights_kernel<<<4096, 256, 0, stream>>>(kern, wk, wq, wvt);

  // Mt[d',d] = sum_e Wk[d',e] * Wq_s[d,e]
  gemm_bt<1><<<dim3(8, 8, 1), 256, 0, stream>>>(wk, 1024, 0, wq, 1024, 0, mt, 1024, 0, 1024);
  // t[q,d'] = sum_d x[q,d] * Mt[d',d]
  gemm_bt<1><<<dim3(8, 128, 1), 256, 0, stream>>>(xbf, 1024, 0, mt, 1024, 0, t, 1024, 0, 1024);
  // vT[b][e,s] = sum_d WvT[e,d] * x_b[s,d]
  gemm_bt<1><<<dim3(32, 8, 4), 256, 0, stream>>>(wvt, 1024, 0,
                                                 xbf, 1024, 4194304,
                                                 vT, 4096, 4194304, 1024);

  for (int b = 0; b < 4; ++b) {
    const ushort_t* xb  = xbf + (long)b * 4194304;
    const ushort_t* vTb = vT  + (long)b * 4194304;
    for (long c0 = 0; c0 < 4096; c0 += CR) {
      const ushort_t* tb = t + ((long)b * 4096 + c0) * 1024;
      // S[q,k] = sum_d' t[q,d'] x_b[k,d']   (fp32 out)
      gemm_bt<0><<<dim3(32, CR / 128, 1), 256, 0, stream>>>(tb, 1024, 0, xb, 1024, 0,
                                                            Sbuf, 4096, 0, 1024);
      softmax_kernel<<<CR, 256, 0, stream>>>(Sbuf);
      // out[q,e] = sum_k P[q,k] vT_b[e,k]; P rows are bf16 packed at 16KB stride
      gemm_bt<0><<<dim3(8, CR / 128, 1), 256, 0, stream>>>((const ushort_t*)Sbuf, 8192, 0,
                                                           vTb, 4096, 0,
                                                           out + ((long)b * 4096 + c0) * 1024, 1024, 0,
                                                           4096);
    }
  }
}

// Round 2
// 724.887 us; speedup vs baseline: 1.0017x; 1.0017x over previous
//
#include <hip/hip_runtime.h>

// ---------------------------------------------------------------------------
// Self-attention, B=4 S=4096 D=DOUT=1024, fp32 in/out.
// scores = x (Wq Wk^T / 32) x^T  -> t = x*M ; S = t x^T  (accuracy trick)
// Round 2: 256^2-tile 8-wave GEMM with counted-vmcnt deep pipeline (T2+T3+T4+T5),
// XCD swizzle (T1), PV batched across b (one 256-block dispatch).
// ---------------------------------------------------------------------------

typedef unsigned short ushort_t;
typedef __attribute__((ext_vector_type(8))) short     bf16x8;
typedef __attribute__((ext_vector_type(4))) float     f32x4;
typedef __attribute__((ext_vector_type(4))) unsigned int u32x4;
typedef __attribute__((ext_vector_type(4))) unsigned short u16x4;

__device__ __forceinline__ unsigned short f2bf(float f) {
  unsigned u = __float_as_uint(f);
  return (unsigned short)((u + 0x7FFFu + ((u >> 16) & 1u)) >> 16);
}

#define GLOAD16(gsrc, ldst)                                                        \
  __builtin_amdgcn_global_load_lds(                                                \
      (const __attribute__((address_space(1))) void*)(gsrc),                       \
      (__attribute__((address_space(3))) void*)(ldst), 16, 0, 0)
#define WAITVM(N) asm volatile("s_waitcnt vmcnt(" #N ")" ::: "memory")
#define SCHED0()  __builtin_amdgcn_sched_barrier(0)
#define BARRIER() __builtin_amdgcn_s_barrier()

// ---------------------------------------------------------------------------
__global__ __launch_bounds__(256) void cast_bf16_kernel(const float* __restrict__ in,
                                                        ushort_t* __restrict__ out) {
  long i = (long)blockIdx.x * 256 + threadIdx.x;
  const f32x4* p = (const f32x4*)(in + i * 8);
  f32x4 a = p[0], b = p[1];
  u32x4 o;
  o.x = (unsigned)f2bf(a[0]) | ((unsigned)f2bf(a[1]) << 16);
  o.y = (unsigned)f2bf(a[2]) | ((unsigned)f2bf(a[3]) << 16);
  o.z = (unsigned)f2bf(b[0]) | ((unsigned)f2bf(b[1]) << 16);
  o.w = (unsigned)f2bf(b[2]) | ((unsigned)f2bf(b[3]) << 16);
  ((u32x4*)out)[i] = o;
}

__global__ __launch_bounds__(256) void prep_weights_kernel(const float* __restrict__ kern,
                                                           ushort_t* __restrict__ wk,
                                                           ushort_t* __restrict__ wq,
                                                           ushort_t* __restrict__ wvt) {
  int idx = blockIdx.x * 256 + threadIdx.x;
  wk[idx] = f2bf(kern[idx]);
  wq[idx] = f2bf(kern[1048576 + idx] * 0.03125f);
  int e = idx >> 10, d = idx & 1023;
  wvt[idx] = f2bf(kern[2097152 + d * 1024 + e]);
}

// ---------------------------------------------------------------------------
// 128^2-tile GEMM (round-1 kernel, kept for the tiny Mt GEMM + low-ws fallback)
template <int OUT_BF16>
__global__ __launch_bounds__(256) void gemm_bt(const ushort_t* __restrict__ A, long lda, long batchA,
                                               const ushort_t* __restrict__ B, long ldb, long batchB,
                                               void* __restrict__ C, long ldc, long batchC,
                                               int K) {
  __shared__ ushort_t lA[128 * 64];
  __shared__ ushort_t lB[128 * 64];

  const int tid  = threadIdx.x;
  const int lane = tid & 63;
  const int wid  = tid >> 6;
  const int wr   = wid >> 1;
  const int wc   = wid & 1;

  const ushort_t* Ab = A + (long)blockIdx.z * batchA + (long)blockIdx.y * 128 * lda;
  const ushort_t* Bb = B + (long)blockIdx.z * batchB + (long)blockIdx.x * 128 * ldb;

  f32x4 acc[4][4] = {};

  const int nkt = K >> 6;
  for (int kt = 0; kt < nkt; ++kt) {
#pragma unroll
    for (int i = 0; i < 4; ++i) {
      int c = tid + i * 256;
      int row = c >> 3, p = c & 7;
      int sc = p ^ (row & 7);
      GLOAD16(Ab + (long)row * lda + kt * 64 + sc * 8, &lA[c * 8]);
    }
#pragma unroll
    for (int i = 0; i < 4; ++i) {
      int c = tid + i * 256;
      int row = c >> 3, p = c & 7;
      int sc = p ^ (row & 7);
      GLOAD16(Bb + (long)row * ldb + kt * 64 + sc * 8, &lB[c * 8]);
    }
    __syncthreads();

    const int lr = lane & 15, lg = lane >> 4;
#pragma unroll
    for (int kk = 0; kk < 2; ++kk) {
      bf16x8 af[4], bfr[4];
#pragma unroll
      for (int m = 0; m < 4; ++m) {
        int row = wr * 64 + m * 16 + lr;
        int cidx = kk * 4 + lg;
        af[m] = *(const bf16x8*)((const char*)lA + row * 128 + ((cidx ^ (row & 7)) << 4));
      }
#pragma unroll
      for (int n = 0; n < 4; ++n) {
        int row = wc * 64 + n * 16 + lr;
        int cidx = kk * 4 + lg;
        bfr[n] = *(const bf16x8*)((const char*)lB + row * 128 + ((cidx ^ (row & 7)) << 4));
      }
#pragma unroll
      for (int m = 0; m < 4; ++m)
#pragma unroll
        for (int n = 0; n < 4; ++n)
          acc[m][n] = __builtin_amdgcn_mfma_f32_16x16x32_bf16(af[m], bfr[n], acc[m][n], 0, 0, 0);
    }
    __syncthreads();
  }

  const long Crow0 = (long)blockIdx.y * 128 + wr * 64;
  const long Ccol0 = (long)blockIdx.x * 128 + wc * 64;
  float*     Cf = (float*)C + (long)blockIdx.z * batchC;
  ushort_t*  Cb = (ushort_t*)C + (long)blockIdx.z * batchC;
#pragma unroll
  for (int m = 0; m < 4; ++m) {
    long r0 = Crow0 + m * 16 + ((lane >> 4) << 2);
#pragma unroll
    for (int n = 0; n < 4; ++n) {
      long cc = Ccol0 + n * 16 + (lane & 15);
#pragma unroll
      for (int j = 0; j < 4; ++j) {
        float val = acc[m][n][j];
        if (OUT_BF16) Cb[(r0 + j) * ldc + cc] = f2bf(val);
        else          Cf[(r0 + j) * ldc + cc] = val;
      }
    }
  }
}

// ---------------------------------------------------------------------------
// 256x256-tile GEMM, BK=64, 512 threads (8 waves, 2Mx4N), counted-vmcnt
// double-buffer pipeline. C[m,n] = sum_k A[m,k]*B[n,k], bf16 in, fp32 acc.
// Grid is 1-D (tx*ty*tz blocks, must be %8==0), XCD-swizzled internally.
template <int OUT_BF16>
__global__ __launch_bounds__(512, 2) void gemm256(
    const ushort_t* __restrict__ A, long lda, long batchA,
    const ushort_t* __restrict__ B, long ldb, long batchB,
    void* __restrict__ C, long ldc, long batchC,
    int K, int tx, int ty) {
  __shared__ ushort_t lds[2][2][16384];   // [dbuf][A/B][256 rows x 64 cols bf16]

  const int nb = gridDim.x;
  int f = blockIdx.x;
  f = (f & 7) * (nb >> 3) + (f >> 3);     // XCD-aware swizzle (nb % 8 == 0)
  const int txy = tx * ty;
  const int bz = f / txy;
  int r = f - bz * txy;
  const int by = r / tx;
  const int bx = r - by * tx;

  const int tid  = threadIdx.x;
  const int lane = tid & 63;
  const int wid  = tid >> 6;
  const int wr   = wid >> 2;              // 0..1 (M half)
  const int wc   = wid & 3;               // 0..3 (N quarter)
  const int lr   = lane & 15, lg = lane >> 4;

  const ushort_t* Ab = A + (long)bz * batchA + (long)by * 256 * lda;
  const ushort_t* Bb = B + (long)bz * batchB + (long)bx * 256 * ldb;

  f32x4 acc[8][4] = {};

  // stage one K-tile (A 32KB + B 32KB): 8 global_load_lds x16B per thread
  auto stage = [&](int buf, int kt) {
    const ushort_t* As = Ab + (long)kt * 64;
    const ushort_t* Bs = Bb + (long)kt * 64;
#pragma unroll
    for (int i = 0; i < 4; ++i) {
      int c = tid + i * 512;              // 16B chunk 0..2047
      int row = c >> 3;
      int sc = (c & 7) ^ (row & 7);       // source-side swizzle, linear LDS dest
      GLOAD16(As + (long)row * lda + sc * 8, &lds[buf][0][c * 8]);
    }
#pragma unroll
    for (int i = 0; i < 4; ++i) {
      int c = tid + i * 512;
      int row = c >> 3;
      int sc = (c & 7) ^ (row & 7);
      GLOAD16(Bs + (long)row * ldb + sc * 8, &lds[buf][1][c * 8]);
    }
  };

  auto compute = [&](int buf) {
#pragma unroll
    for (int kkt = 0; kkt < 2; ++kkt) {
      bf16x8 a[8], b[4];
#pragma unroll
      for (int m = 0; m < 8; ++m) {
        int row = wr * 128 + m * 16 + lr;
        a[m] = *(const bf16x8*)((const char*)&lds[buf][0][0] + row * 128 +
                                (((kkt * 4 + lg) ^ (row & 7)) << 4));
      }
#pragma unroll
      for (int n = 0; n < 4; ++n) {
        int row = wc * 64 + n * 16 + lr;
        b[n] = *(const bf16x8*)((const char*)&lds[buf][1][0] + row * 128 +
                                (((kkt * 4 + lg) ^ (row & 7)) << 4));
      }
      __builtin_amdgcn_s_setprio(1);
#pragma unroll
      for (int m = 0; m < 8; ++m)
#pragma unroll
        for (int n = 0; n < 4; ++n)
          acc[m][n] = __builtin_amdgcn_mfma_f32_16x16x32_bf16(a[m], b[n], acc[m][n], 0, 0, 0);
      __builtin_amdgcn_s_setprio(0);
    }
  };

  const int nkt = K >> 6;                 // always >= 16 here
  stage(0, 0);
  stage(1, 1);
  WAITVM(8);                              // tile 0 landed (tile 1 in flight)
  BARRIER();
  SCHED0();
  for (int kt = 0; kt < nkt; ++kt) {
    compute(kt & 1);
    BARRIER();                            // all waves done reading buf kt&1
    SCHED0();
    if (kt + 2 < nkt) {
      stage(kt & 1, kt + 2);              // overwrite freed buffer
      WAITVM(8);                          // tile kt+1 drained; kt+2 in flight
    } else {
      WAITVM(0);                          // tail: drain everything
    }
    BARRIER();                            // tile kt+1 visible to all waves
    SCHED0();
  }

  // epilogue: C/D frag layout col=lane&15, row=(lane>>4)*4+j
  const long Crow0 = (long)by * 256 + wr * 128;
  const long Ccol0 = (long)bx * 256 + wc * 64;
  float*     Cf = (float*)C + (long)bz * batchC;
  ushort_t*  Cb = (ushort_t*)C + (long)bz * batchC;
#pragma unroll
  for (int m = 0; m < 8; ++m) {
    long r0 = Crow0 + m * 16 + ((lane >> 4) << 2);
#pragma unroll
    for (int n = 0; n < 4; ++n) {
      long cc = Ccol0 + n * 16 + (lane & 15);
#pragma unroll
      for (int j = 0; j < 4; ++j) {
        float val = acc[m][n][j];
        if (OUT_BF16) Cb[(r0 + j) * ldc + cc] = f2bf(val);
        else          Cf[(r0 + j) * ldc + cc] = val;
      }
    }
  }
}

// ---------------------------------------------------------------------------
// row softmax over 4096 fp32 scores; write normalized P bf16 to P+row*pstride
__global__ __launch_bounds__(256) void softmax_kernel(float* __restrict__ S,
                                                      ushort_t* __restrict__ P,
                                                      long pstride) {
  float* row = S + (long)blockIdx.x * 4096;
  const int tid = threadIdx.x;
  __shared__ float red[4];

  f32x4 v[4];
#pragma unroll
  for (int i = 0; i < 4; ++i) v[i] = ((const f32x4*)row)[tid + i * 256];

  float m = -1e30f;
#pragma unroll
  for (int i = 0; i < 4; ++i)
#pragma unroll
    for (int j = 0; j < 4; ++j) m = fmaxf(m, v[i][j]);
  for (int o = 32; o; o >>= 1) m = fmaxf(m, __shfl_xor(m, o));
  if ((tid & 63) == 0) red[tid >> 6] = m;
  __syncthreads();
  m = fmaxf(fmaxf(red[0], red[1]), fmaxf(red[2], red[3]));

  float p[16];
  float s = 0.f;
#pragma unroll
  for (int i = 0; i < 4; ++i)
#pragma unroll
    for (int j = 0; j < 4; ++j) {
      float e = __expf(v[i][j] - m);
      p[i * 4 + j] = e;
      s += e;
    }
  for (int o = 32; o; o >>= 1) s += __shfl_xor(s, o);
  __syncthreads();
  if ((tid & 63) == 0) red[tid >> 6] = s;
  __syncthreads();
  s = red[0] + red[1] + red[2] + red[3];
  float inv = 1.0f / s;

  u16x4* prow = (u16x4*)(P + (long)blockIdx.x * pstride);
#pragma unroll
  for (int i = 0; i < 4; ++i) {
    u16x4 o;
    o.x = f2bf(p[i * 4 + 0] * inv);
    o.y = f2bf(p[i * 4 + 1] * inv);
    o.z = f2bf(p[i * 4 + 2] * inv);
    o.w = f2bf(p[i * 4 + 3] * inv);
    prow[tid + i * 256] = o;
  }
}

// ---------------------------------------------------------------------------
extern "C" void kernel_launch(void* const* d_in, const int* in_sizes, int n_in,
                              void* d_out, int out_size, void* d_ws, size_t ws_size,
                              hipStream_t stream) {
  const float* x    = (const float*)d_in[0];   // [4,4096,1024]
  const float* kern = (const float*)d_in[1];   // [3,1024,1024]
  float* out = (float*)d_out;                  // [4,4096,1024]

  char* p = (char*)d_ws;
  ushort_t* xbf = (ushort_t*)p; p += 33554432;         // 16384x1024 bf16
  ushort_t* t   = (ushort_t*)p; p += 33554432;         // 16384x1024 bf16
  ushort_t* vT  = (ushort_t*)p; p += 33554432;         // 4x1024x4096 bf16
  ushort_t* wk  = (ushort_t*)p; p += 2097152;
  ushort_t* wq  = (ushort_t*)p; p += 2097152;
  ushort_t* wvt = (ushort_t*)p; p += 2097152;
  ushort_t* mt  = (ushort_t*)p; p += 2097152;
  size_t fixed = (size_t)(p - (char*)d_ws);            // 104 MiB

  cast_bf16_kernel<<<8192, 256, 0, stream>>>(x, xbf);
  prep_weights_kernel<<<4096, 256, 0, stream>>>(kern, wk, wq, wvt);
  // Mt[d',d] = sum_e Wk[d',e] * Wq_s[d,e]  (tiny; 128^2 kernel)
  gemm_bt<1><<<dim3(8, 8, 1), 256, 0, stream>>>(wk, 1024, 0, wq, 1024, 0, mt, 1024, 0, 1024);

  const size_t needA = fixed + 67108864ull + 134217728ull;  // + Sbuf fp32 + dense P x4
  if (ws_size >= needA) {
    float*    Sbuf = (float*)p;    p += 67108864;      // 4096x4096 fp32 (reused per b)
    ushort_t* Pbuf = (ushort_t*)p;                     // 4 x 4096x4096 bf16

    // t[q,d'] = sum_d x[q,d] * Mt[d',d]
    gemm256<1><<<dim3(256), dim3(512), 0, stream>>>(xbf, 1024, 0, mt, 1024, 0,
                                                    t, 1024, 0, 1024, 4, 64);
    // vT[b][e,s] = sum_d WvT[e,d] * x_b[s,d]
    gemm256<1><<<dim3(256), dim3(512), 0, stream>>>(wvt, 1024, 0,
                                                    xbf, 1024, 4194304,
                                                    vT, 4096, 4194304, 1024, 16, 4);
    for (int b = 0; b < 4; ++b) {
      // S[q,k] = sum_d' t_b[q,d'] x_b[k,d']
      gemm256<0><<<dim3(256), dim3(512), 0, stream>>>(t + (long)b * 4194304, 1024, 0,
                                                      xbf + (long)b * 4194304, 1024, 0,
                                                      Sbuf, 4096, 0, 1024, 16, 16);
      softmax_kernel<<<4096, 256, 0, stream>>>(Sbuf, Pbuf + (long)b * 16777216, 4096);
    }
    // out[b][q,e] = sum_k P_b[q,k] vT_b[e,k]   — one batched 256-block dispatch
    gemm256<0><<<dim3(256), dim3(512), 0, stream>>>(Pbuf, 4096, 16777216,
                                                    vT, 4096, 4194304,
                                                    out, 1024, 4194304, 4096, 4, 16);
  } else {
    // -------- round-1 fallback (chunked, in-place packed P) --------
    float* Sbuf = (float*)p;
    long CR = 4096;
    while (CR > 256 && fixed + (size_t)CR * 4096 * 4 > ws_size) CR >>= 1;

    gemm_bt<1><<<dim3(8, 128, 1), 256, 0, stream>>>(xbf, 1024, 0, mt, 1024, 0, t, 1024, 0, 1024);
    gemm_bt<1><<<dim3(32, 8, 4), 256, 0, stream>>>(wvt, 1024, 0,
                                                   xbf, 1024, 4194304,
                                                   vT, 4096, 4194304, 1024);
    for (int b = 0; b < 4; ++b) {
      const ushort_t* xb  = xbf + (long)b * 4194304;
      const ushort_t* vTb = vT  + (long)b * 4194304;
      for (long c0 = 0; c0 < 4096; c0 += CR) {
        const ushort_t* tb = t + ((long)b * 4096 + c0) * 1024;
        gemm_bt<0><<<dim3(32, CR / 128, 1), 256, 0, stream>>>(tb, 1024, 0, xb, 1024, 0,
                                                              Sbuf, 4096, 0, 1024);
        softmax_kernel<<<CR, 256, 0, stream>>>(Sbuf, (ushort_t*)Sbuf, 8192);
        gemm_bt<0><<<dim3(8, CR / 128, 1), 256, 0, stream>>>((const ushort_t*)Sbuf, 8192, 0,
                                                             vTb, 4096, 0,
                                                             out + ((long)b * 4096 + c0) * 1024, 1024, 0,
                                                             4096);
      }
    }
  }
}

// Round 3
// 427.988 us; speedup vs baseline: 1.6966x; 1.6937x over previous
//
#include <hip/hip_runtime.h>

// ---------------------------------------------------------------------------
// Self-attention, B=4 S=4096 D=DOUT=1024, fp32 in/out.
// scores = x (Wq Wk^T / 32) x^T  -> t = x*M ; S = t x^T  (accuracy trick)
// Round 3: S stored bf16 (32MB/b) so all 4 P buffers fit -> batched 256-block
// PV with the 256^2 8-wave counted-vmcnt pipeline. ws-adaptive branches.
// ---------------------------------------------------------------------------

typedef unsigned short ushort_t;
typedef __attribute__((ext_vector_type(8))) short     bf16x8;
typedef __attribute__((ext_vector_type(4))) float     f32x4;
typedef __attribute__((ext_vector_type(4))) unsigned int u32x4;
typedef __attribute__((ext_vector_type(4))) unsigned short u16x4;

__device__ __forceinline__ unsigned short f2bf(float f) {
  unsigned u = __float_as_uint(f);
  return (unsigned short)((u + 0x7FFFu + ((u >> 16) & 1u)) >> 16);
}
__device__ __forceinline__ float bf2f(unsigned short h) {
  return __uint_as_float((unsigned)h << 16);
}

#define GLOAD16(gsrc, ldst)                                                        \
  __builtin_amdgcn_global_load_lds(                                                \
      (const __attribute__((address_space(1))) void*)(gsrc),                       \
      (__attribute__((address_space(3))) void*)(ldst), 16, 0, 0)
#define WAITVM(N) asm volatile("s_waitcnt vmcnt(" #N ")" ::: "memory")
#define WAITLGKM0() asm volatile("s_waitcnt lgkmcnt(0)" ::: "memory")
#define SCHED0()  __builtin_amdgcn_sched_barrier(0)
#define BARRIER() __builtin_amdgcn_s_barrier()

// ---------------------------------------------------------------------------
__global__ __launch_bounds__(256) void cast_bf16_kernel(const float* __restrict__ in,
                                                        ushort_t* __restrict__ out) {
  long i = (long)blockIdx.x * 256 + threadIdx.x;
  const f32x4* p = (const f32x4*)(in + i * 8);
  f32x4 a = p[0], b = p[1];
  u32x4 o;
  o.x = (unsigned)f2bf(a[0]) | ((unsigned)f2bf(a[1]) << 16);
  o.y = (unsigned)f2bf(a[2]) | ((unsigned)f2bf(a[3]) << 16);
  o.z = (unsigned)f2bf(b[0]) | ((unsigned)f2bf(b[1]) << 16);
  o.w = (unsigned)f2bf(b[2]) | ((unsigned)f2bf(b[3]) << 16);
  ((u32x4*)out)[i] = o;
}

__global__ __launch_bounds__(256) void prep_weights_kernel(const float* __restrict__ kern,
                                                           ushort_t* __restrict__ wk,
                                                           ushort_t* __restrict__ wq,
                                                           ushort_t* __restrict__ wvt) {
  int idx = blockIdx.x * 256 + threadIdx.x;
  wk[idx] = f2bf(kern[idx]);
  wq[idx] = f2bf(kern[1048576 + idx] * 0.03125f);
  int e = idx >> 10, d = idx & 1023;
  wvt[idx] = f2bf(kern[2097152 + d * 1024 + e]);
}

// ---------------------------------------------------------------------------
// 128^2-tile GEMM (kept for the tiny Mt GEMM + low-ws fallback)
template <int OUT_BF16>
__global__ __launch_bounds__(256) void gemm_bt(const ushort_t* __restrict__ A, long lda, long batchA,
                                               const ushort_t* __restrict__ B, long ldb, long batchB,
                                               void* __restrict__ C, long ldc, long batchC,
                                               int K) {
  __shared__ ushort_t lA[128 * 64];
  __shared__ ushort_t lB[128 * 64];

  const int tid  = threadIdx.x;
  const int lane = tid & 63;
  const int wid  = tid >> 6;
  const int wr   = wid >> 1;
  const int wc   = wid & 1;

  const ushort_t* Ab = A + (long)blockIdx.z * batchA + (long)blockIdx.y * 128 * lda;
  const ushort_t* Bb = B + (long)blockIdx.z * batchB + (long)blockIdx.x * 128 * ldb;

  f32x4 acc[4][4] = {};

  const int nkt = K >> 6;
  for (int kt = 0; kt < nkt; ++kt) {
#pragma unroll
    for (int i = 0; i < 4; ++i) {
      int c = tid + i * 256;
      int row = c >> 3, p = c & 7;
      int sc = p ^ (row & 7);
      GLOAD16(Ab + (long)row * lda + kt * 64 + sc * 8, &lA[c * 8]);
    }
#pragma unroll
    for (int i = 0; i < 4; ++i) {
      int c = tid + i * 256;
      int row = c >> 3, p = c & 7;
      int sc = p ^ (row & 7);
      GLOAD16(Bb + (long)row * ldb + kt * 64 + sc * 8, &lB[c * 8]);
    }
    __syncthreads();

    const int lr = lane & 15, lg = lane >> 4;
#pragma unroll
    for (int kk = 0; kk < 2; ++kk) {
      bf16x8 af[4], bfr[4];
#pragma unroll
      for (int m = 0; m < 4; ++m) {
        int row = wr * 64 + m * 16 + lr;
        int cidx = kk * 4 + lg;
        af[m] = *(const bf16x8*)((const char*)lA + row * 128 + ((cidx ^ (row & 7)) << 4));
      }
#pragma unroll
      for (int n = 0; n < 4; ++n) {
        int row = wc * 64 + n * 16 + lr;
        int cidx = kk * 4 + lg;
        bfr[n] = *(const bf16x8*)((const char*)lB + row * 128 + ((cidx ^ (row & 7)) << 4));
      }
#pragma unroll
      for (int m = 0; m < 4; ++m)
#pragma unroll
        for (int n = 0; n < 4; ++n)
          acc[m][n] = __builtin_amdgcn_mfma_f32_16x16x32_bf16(af[m], bfr[n], acc[m][n], 0, 0, 0);
    }
    __syncthreads();
  }

  const long Crow0 = (long)blockIdx.y * 128 + wr * 64;
  const long Ccol0 = (long)blockIdx.x * 128 + wc * 64;
  float*     Cf = (float*)C + (long)blockIdx.z * batchC;
  ushort_t*  Cb = (ushort_t*)C + (long)blockIdx.z * batchC;
#pragma unroll
  for (int m = 0; m < 4; ++m) {
    long r0 = Crow0 + m * 16 + ((lane >> 4) << 2);
#pragma unroll
    for (int n = 0; n < 4; ++n) {
      long cc = Ccol0 + n * 16 + (lane & 15);
#pragma unroll
      for (int j = 0; j < 4; ++j) {
        float val = acc[m][n][j];
        if (OUT_BF16) Cb[(r0 + j) * ldc + cc] = f2bf(val);
        else          Cf[(r0 + j) * ldc + cc] = val;
      }
    }
  }
}

// ---------------------------------------------------------------------------
// 256x256-tile GEMM, BK=64, 512 threads (8 waves, 2Mx4N), counted-vmcnt
// double-buffer pipeline. C[m,n] = sum_k A[m,k]*B[n,k], bf16 in, fp32 acc.
// Grid is 1-D (tx*ty*bz blocks, must be %8==0), XCD-swizzled internally.
template <int OUT_BF16>
__global__ __launch_bounds__(512, 2) void gemm256(
    const ushort_t* __restrict__ A, long lda, long batchA,
    const ushort_t* __restrict__ B, long ldb, long batchB,
    void* __restrict__ C, long ldc, long batchC,
    int K, int tx, int ty) {
  __shared__ ushort_t lds[2][2][16384];   // [dbuf][A/B][256 rows x 64 cols bf16]

  const int nb = gridDim.x;
  int f = blockIdx.x;
  f = (f & 7) * (nb >> 3) + (f >> 3);     // XCD-aware swizzle (nb % 8 == 0)
  const int txy = tx * ty;
  const int bz = f / txy;
  int r = f - bz * txy;
  const int by = r / tx;
  const int bx = r - by * tx;

  const int tid  = threadIdx.x;
  const int lane = tid & 63;
  const int wid  = tid >> 6;
  const int wr   = wid >> 2;              // 0..1 (M half)
  const int wc   = wid & 3;               // 0..3 (N quarter)
  const int lr   = lane & 15, lg = lane >> 4;

  const ushort_t* Ab = A + (long)bz * batchA + (long)by * 256 * lda;
  const ushort_t* Bb = B + (long)bz * batchB + (long)bx * 256 * ldb;

  f32x4 acc[8][4] = {};

  // stage one K-tile (A 32KB + B 32KB): 8 global_load_lds x16B per thread
  auto stage = [&](int buf, int kt) {
    const ushort_t* As = Ab + (long)kt * 64;
    const ushort_t* Bs = Bb + (long)kt * 64;
#pragma unroll
    for (int i = 0; i < 4; ++i) {
      int c = tid + i * 512;              // 16B chunk 0..2047
      int row = c >> 3;
      int sc = (c & 7) ^ (row & 7);       // source-side swizzle, linear LDS dest
      GLOAD16(As + (long)row * lda + sc * 8, &lds[buf][0][c * 8]);
    }
#pragma unroll
    for (int i = 0; i < 4; ++i) {
      int c = tid + i * 512;
      int row = c >> 3;
      int sc = (c & 7) ^ (row & 7);
      GLOAD16(Bs + (long)row * ldb + sc * 8, &lds[buf][1][c * 8]);
    }
  };

  auto compute = [&](int buf) {
#pragma unroll
    for (int kkt = 0; kkt < 2; ++kkt) {
      bf16x8 a[8], b[4];
#pragma unroll
      for (int m = 0; m < 8; ++m) {
        int row = wr * 128 + m * 16 + lr;
        a[m] = *(const bf16x8*)((const char*)&lds[buf][0][0] + row * 128 +
                                (((kkt * 4 + lg) ^ (row & 7)) << 4));
      }
#pragma unroll
      for (int n = 0; n < 4; ++n) {
        int row = wc * 64 + n * 16 + lr;
        b[n] = *(const bf16x8*)((const char*)&lds[buf][1][0] + row * 128 +
                                (((kkt * 4 + lg) ^ (row & 7)) << 4));
      }
      __builtin_amdgcn_s_setprio(1);
#pragma unroll
      for (int m = 0; m < 8; ++m)
#pragma unroll
        for (int n = 0; n < 4; ++n)
          acc[m][n] = __builtin_amdgcn_mfma_f32_16x16x32_bf16(a[m], b[n], acc[m][n], 0, 0, 0);
      __builtin_amdgcn_s_setprio(0);
    }
  };

  const int nkt = K >> 6;                 // always >= 16 here
  stage(0, 0);
  stage(1, 1);
  WAITVM(8);                              // tile 0 landed (tile 1 in flight)
  BARRIER();
  SCHED0();
  for (int kt = 0; kt < nkt; ++kt) {
    compute(kt & 1);
    WAITLGKM0();                          // all ds_reads serviced before overwrite
    SCHED0();
    BARRIER();                            // all waves done reading buf kt&1
    SCHED0();
    if (kt + 2 < nkt) {
      stage(kt & 1, kt + 2);              // overwrite freed buffer
      WAITVM(8);                          // tile kt+1 drained; kt+2 in flight
    } else {
      WAITVM(0);                          // tail: drain everything
    }
    BARRIER();                            // tile kt+1 visible to all waves
    SCHED0();
  }

  // epilogue: C/D frag layout col=lane&15, row=(lane>>4)*4+j
  const long Crow0 = (long)by * 256 + wr * 128;
  const long Ccol0 = (long)bx * 256 + wc * 64;
  float*     Cf = (float*)C + (long)bz * batchC;
  ushort_t*  Cb = (ushort_t*)C + (long)bz * batchC;
#pragma unroll
  for (int m = 0; m < 8; ++m) {
    long r0 = Crow0 + m * 16 + ((lane >> 4) << 2);
#pragma unroll
    for (int n = 0; n < 4; ++n) {
      long cc = Ccol0 + n * 16 + (lane & 15);
#pragma unroll
      for (int j = 0; j < 4; ++j) {
        float val = acc[m][n][j];
        if (OUT_BF16) Cb[(r0 + j) * ldc + cc] = f2bf(val);
        else          Cf[(r0 + j) * ldc + cc] = val;
      }
    }
  }
}

// ---------------------------------------------------------------------------
// row softmax over 4096 fp32 scores; write normalized P bf16 to P+row*pstride
__global__ __launch_bounds__(256) void softmax_kernel(float* __restrict__ S,
                                                      ushort_t* __restrict__ P,
                                                      long pstride) {
  float* row = S + (long)blockIdx.x * 4096;
  const int tid = threadIdx.x;
  __shared__ float red[4];

  f32x4 v[4];
#pragma unroll
  for (int i = 0; i < 4; ++i) v[i] = ((const f32x4*)row)[tid + i * 256];

  float m = -1e30f;
#pragma unroll
  for (int i = 0; i < 4; ++i)
#pragma unroll
    for (int j = 0; j < 4; ++j) m = fmaxf(m, v[i][j]);
  for (int o = 32; o; o >>= 1) m = fmaxf(m, __shfl_xor(m, o));
  if ((tid & 63) == 0) red[tid >> 6] = m;
  __syncthreads();
  m = fmaxf(fmaxf(red[0], red[1]), fmaxf(red[2], red[3]));

  float p[16];
  float s = 0.f;
#pragma unroll
  for (int i = 0; i < 4; ++i)
#pragma unroll
    for (int j = 0; j < 4; ++j) {
      float e = __expf(v[i][j] - m);
      p[i * 4 + j] = e;
      s += e;
    }
  for (int o = 32; o; o >>= 1) s += __shfl_xor(s, o);
  __syncthreads();
  if ((tid & 63) == 0) red[tid >> 6] = s;
  __syncthreads();
  s = red[0] + red[1] + red[2] + red[3];
  float inv = 1.0f / s;

  u16x4* prow = (u16x4*)(P + (long)blockIdx.x * pstride);
#pragma unroll
  for (int i = 0; i < 4; ++i) {
    u16x4 o;
    o.x = f2bf(p[i * 4 + 0] * inv);
    o.y = f2bf(p[i * 4 + 1] * inv);
    o.z = f2bf(p[i * 4 + 2] * inv);
    o.w = f2bf(p[i * 4 + 3] * inv);
    prow[tid + i * 256] = o;
  }
}

// row softmax over 4096 bf16 scores, P bf16 written IN PLACE (row-local, no race)
__global__ __launch_bounds__(256) void softmax_bf16_kernel(ushort_t* __restrict__ S) {
  u16x4* row = (u16x4*)(S + (long)blockIdx.x * 4096);   // 1024 u16x4 per row
  const int tid = threadIdx.x;
  __shared__ float red[4];

  float v[16];
#pragma unroll
  for (int i = 0; i < 4; ++i) {
    u16x4 h = row[tid + i * 256];
    v[i * 4 + 0] = bf2f(h.x); v[i * 4 + 1] = bf2f(h.y);
    v[i * 4 + 2] = bf2f(h.z); v[i * 4 + 3] = bf2f(h.w);
  }

  float m = -1e30f;
#pragma unroll
  for (int i = 0; i < 16; ++i) m = fmaxf(m, v[i]);
  for (int o = 32; o; o >>= 1) m = fmaxf(m, __shfl_xor(m, o));
  if ((tid & 63) == 0) red[tid >> 6] = m;
  __syncthreads();
  m = fmaxf(fmaxf(red[0], red[1]), fmaxf(red[2], red[3]));

  float s = 0.f;
#pragma unroll
  for (int i = 0; i < 16; ++i) {
    v[i] = __expf(v[i] - m);
    s += v[i];
  }
  for (int o = 32; o; o >>= 1) s += __shfl_xor(s, o);
  __syncthreads();
  if ((tid & 63) == 0) red[tid >> 6] = s;
  __syncthreads();
  s = red[0] + red[1] + red[2] + red[3];
  float inv = 1.0f / s;

#pragma unroll
  for (int i = 0; i < 4; ++i) {
    u16x4 o;
    o.x = f2bf(v[i * 4 + 0] * inv);
    o.y = f2bf(v[i * 4 + 1] * inv);
    o.z = f2bf(v[i * 4 + 2] * inv);
    o.w = f2bf(v[i * 4 + 3] * inv);
    row[tid + i * 256] = o;
  }
}

// ---------------------------------------------------------------------------
extern "C" void kernel_launch(void* const* d_in, const int* in_sizes, int n_in,
                              void* d_out, int out_size, void* d_ws, size_t ws_size,
                              hipStream_t stream) {
  const float* x    = (const float*)d_in[0];   // [4,4096,1024]
  const float* kern = (const float*)d_in[1];   // [3,1024,1024]
  float* out = (float*)d_out;                  // [4,4096,1024]

  char* p = (char*)d_ws;
  ushort_t* xbf = (ushort_t*)p; p += 33554432;         // 16384x1024 bf16
  ushort_t* t   = (ushort_t*)p; p += 33554432;         // 16384x1024 bf16
  ushort_t* vT  = (ushort_t*)p; p += 33554432;         // 4x1024x4096 bf16
  ushort_t* wk  = (ushort_t*)p; p += 2097152;
  ushort_t* wq  = (ushort_t*)p; p += 2097152;
  ushort_t* wvt = (ushort_t*)p; p += 2097152;
  ushort_t* mt  = (ushort_t*)p; p += 2097152;
  size_t fixed = (size_t)(p - (char*)d_ws);            // 104 MiB

  cast_bf16_kernel<<<8192, 256, 0, stream>>>(x, xbf);
  prep_weights_kernel<<<4096, 256, 0, stream>>>(kern, wk, wq, wvt);
  // Mt[d',d] = sum_e Wk[d',e] * Wq_s[d,e]  (tiny; 128^2 kernel)
  gemm_bt<1><<<dim3(8, 8, 1), 256, 0, stream>>>(wk, 1024, 0, wq, 1024, 0, mt, 1024, 0, 1024);

  const size_t need4 = fixed + 4ull * 33554432;        // 4 bf16 S/P buffers (232 MiB)
  const size_t need2 = fixed + 2ull * 33554432;        // 2 bf16 S/P buffers (168 MiB)

  if (ws_size >= need2) {
    ushort_t* Sb = (ushort_t*)p;                       // 2 or 4 x (4096x4096 bf16)

    // t[q,d'] = sum_d x[q,d] * Mt[d',d]      grid 4x64 = 256
    gemm256<1><<<dim3(256), dim3(512), 0, stream>>>(xbf, 1024, 0, mt, 1024, 0,
                                                    t, 1024, 0, 1024, 4, 64);
    // vT[b][e,s] = sum_d WvT[e,d] * x_b[s,d]  grid 16x4x4 = 256
    gemm256<1><<<dim3(256), dim3(512), 0, stream>>>(wvt, 1024, 0,
                                                    xbf, 1024, 4194304,
                                                    vT, 4096, 4194304, 1024, 16, 4);

    const int nb_at_once = (ws_size >= need4) ? 4 : 2;
    for (int b0 = 0; b0 < 4; b0 += nb_at_once) {
      for (int b = b0; b < b0 + nb_at_once; ++b) {
        // S_b[q,k] = sum_d' t_b[q,d'] x_b[k,d']  (bf16 out)  grid 16x16 = 256
        gemm256<1><<<dim3(256), dim3(512), 0, stream>>>(
            t + (long)b * 4194304, 1024, 0,
            xbf + (long)b * 4194304, 1024, 0,
            Sb + (long)(b - b0) * 16777216, 4096, 0, 1024, 16, 16);
      }
      // softmax all staged rows in one dispatch (in-place bf16 P)
      softmax_bf16_kernel<<<4096 * nb_at_once, 256, 0, stream>>>(Sb);
      // out[b][q,e] = sum_k P_b[q,k] vT_b[e,k]  grid 4x16xnb
      gemm256<0><<<dim3(4 * 16 * nb_at_once), dim3(512), 0, stream>>>(
          Sb, 4096, 16777216,
          vT + (long)b0 * 4194304, 4096, 4194304,
          out + (long)b0 * 4194304, 1024, 4194304, 4096, 4, 16);
    }
  } else {
    // -------- round-1 fallback (chunked, in-place packed P) --------
    float* Sbuf = (float*)p;
    long CR = 4096;
    while (CR > 256 && fixed + (size_t)CR * 4096 * 4 > ws_size) CR >>= 1;

    gemm_bt<1><<<dim3(8, 128, 1), 256, 0, stream>>>(xbf, 1024, 0, mt, 1024, 0, t, 1024, 0, 1024);
    gemm_bt<1><<<dim3(32, 8, 4), 256, 0, stream>>>(wvt, 1024, 0,
                                                   xbf, 1024, 4194304,
                                                   vT, 4096, 4194304, 1024);
    for (int b = 0; b < 4; ++b) {
      const ushort_t* xb  = xbf + (long)b * 4194304;
      const ushort_t* vTb = vT  + (long)b * 4194304;
      for (long c0 = 0; c0 < 4096; c0 += CR) {
        const ushort_t* tb = t + ((long)b * 4096 + c0) * 1024;
        gemm_bt<0><<<dim3(32, CR / 128, 1), 256, 0, stream>>>(tb, 1024, 0, xb, 1024, 0,
                                                              Sbuf, 4096, 0, 1024);
        softmax_kernel<<<CR, 256, 0, stream>>>(Sbuf, (ushort_t*)Sbuf, 8192);
        gemm_bt<0><<<dim3(8, CR / 128, 1), 256, 0, stream>>>((const ushort_t*)Sbuf, 8192, 0,
                                                             vTb, 4096, 0,
                                                             out + ((long)b * 4096 + c0) * 1024, 1024, 0,
                                                             4096);
      }
    }
  }
}

// Round 4
// 412.178 us; speedup vs baseline: 1.7616x; 1.0384x over previous
//
#include <hip/hip_runtime.h>

// ---------------------------------------------------------------------------
// Self-attention, B=4 S=4096 D=DOUT=1024, fp32 in/out.
// scores = x (Wq Wk^T / 32) x^T  -> t = x*M ; S = t x^T  (accuracy trick)
// Round 4: gemm256 rebuilt as 4-phase/K-tile fine interleave (T3+T4+T5):
//   phase p: [ds_read quadrant frags][issue 2 half-stripe gload_lds]
//            [barrier][vmcnt(6)][lgkmcnt(0)][16 MFMA][barrier]
//   stripe ledger: min issue->consume lag = 4 phases; vmcnt(6)@g-1+barrier
//   guarantees all waves' loads <= g-4 landed. Prologue 12 loads + vmcnt(4);
//   tail waits {6,6,6,4}/{0,0,0,0}.
// ---------------------------------------------------------------------------

typedef unsigned short ushort_t;
typedef __attribute__((ext_vector_type(8))) short     bf16x8;
typedef __attribute__((ext_vector_type(4))) float     f32x4;
typedef __attribute__((ext_vector_type(4))) unsigned int u32x4;
typedef __attribute__((ext_vector_type(4))) unsigned short u16x4;

__device__ __forceinline__ unsigned short f2bf(float f) {
  unsigned u = __float_as_uint(f);
  return (unsigned short)((u + 0x7FFFu + ((u >> 16) & 1u)) >> 16);
}
__device__ __forceinline__ float bf2f(unsigned short h) {
  return __uint_as_float((unsigned)h << 16);
}

#define GLOAD16(gsrc, ldst)                                                        \
  __builtin_amdgcn_global_load_lds(                                                \
      (const __attribute__((address_space(1))) void*)(gsrc),                       \
      (__attribute__((address_space(3))) void*)(ldst), 16, 0, 0)
#define WAITVM(N) asm volatile("s_waitcnt vmcnt(" #N ")" ::: "memory")
#define WAITLGKM0() asm volatile("s_waitcnt lgkmcnt(0)" ::: "memory")
#define SCHED0()  __builtin_amdgcn_sched_barrier(0)
#define BARRIER() __builtin_amdgcn_s_barrier()

// ---------------------------------------------------------------------------
__global__ __launch_bounds__(256) void cast_bf16_kernel(const float* __restrict__ in,
                                                        ushort_t* __restrict__ out) {
  long i = (long)blockIdx.x * 256 + threadIdx.x;
  const f32x4* p = (const f32x4*)(in + i * 8);
  f32x4 a = p[0], b = p[1];
  u32x4 o;
  o.x = (unsigned)f2bf(a[0]) | ((unsigned)f2bf(a[1]) << 16);
  o.y = (unsigned)f2bf(a[2]) | ((unsigned)f2bf(a[3]) << 16);
  o.z = (unsigned)f2bf(b[0]) | ((unsigned)f2bf(b[1]) << 16);
  o.w = (unsigned)f2bf(b[2]) | ((unsigned)f2bf(b[3]) << 16);
  ((u32x4*)out)[i] = o;
}

__global__ __launch_bounds__(256) void prep_weights_kernel(const float* __restrict__ kern,
                                                           ushort_t* __restrict__ wk,
                                                           ushort_t* __restrict__ wq,
                                                           ushort_t* __restrict__ wvt) {
  int idx = blockIdx.x * 256 + threadIdx.x;
  wk[idx] = f2bf(kern[idx]);
  wq[idx] = f2bf(kern[1048576 + idx] * 0.03125f);
  int e = idx >> 10, d = idx & 1023;
  wvt[idx] = f2bf(kern[2097152 + d * 1024 + e]);
}

// ---------------------------------------------------------------------------
// 128^2-tile GEMM (kept for the tiny Mt GEMM + low-ws fallback)
template <int OUT_BF16>
__global__ __launch_bounds__(256) void gemm_bt(const ushort_t* __restrict__ A, long lda, long batchA,
                                               const ushort_t* __restrict__ B, long ldb, long batchB,
                                               void* __restrict__ C, long ldc, long batchC,
                                               int K) {
  __shared__ ushort_t lA[128 * 64];
  __shared__ ushort_t lB[128 * 64];

  const int tid  = threadIdx.x;
  const int lane = tid & 63;
  const int wid  = tid >> 6;
  const int wr   = wid >> 1;
  const int wc   = wid & 1;

  const ushort_t* Ab = A + (long)blockIdx.z * batchA + (long)blockIdx.y * 128 * lda;
  const ushort_t* Bb = B + (long)blockIdx.z * batchB + (long)blockIdx.x * 128 * ldb;

  f32x4 acc[4][4] = {};

  const int nkt = K >> 6;
  for (int kt = 0; kt < nkt; ++kt) {
#pragma unroll
    for (int i = 0; i < 4; ++i) {
      int c = tid + i * 256;
      int row = c >> 3, p = c & 7;
      int sc = p ^ (row & 7);
      GLOAD16(Ab + (long)row * lda + kt * 64 + sc * 8, &lA[c * 8]);
    }
#pragma unroll
    for (int i = 0; i < 4; ++i) {
      int c = tid + i * 256;
      int row = c >> 3, p = c & 7;
      int sc = p ^ (row & 7);
      GLOAD16(Bb + (long)row * ldb + kt * 64 + sc * 8, &lB[c * 8]);
    }
    __syncthreads();

    const int lr = lane & 15, lg = lane >> 4;
#pragma unroll
    for (int kk = 0; kk < 2; ++kk) {
      bf16x8 af[4], bfr[4];
#pragma unroll
      for (int m = 0; m < 4; ++m) {
        int row = wr * 64 + m * 16 + lr;
        int cidx = kk * 4 + lg;
        af[m] = *(const bf16x8*)((const char*)lA + row * 128 + ((cidx ^ (row & 7)) << 4));
      }
#pragma unroll
      for (int n = 0; n < 4; ++n) {
        int row = wc * 64 + n * 16 + lr;
        int cidx = kk * 4 + lg;
        bfr[n] = *(const bf16x8*)((const char*)lB + row * 128 + ((cidx ^ (row & 7)) << 4));
      }
#pragma unroll
      for (int m = 0; m < 4; ++m)
#pragma unroll
        for (int n = 0; n < 4; ++n)
          acc[m][n] = __builtin_amdgcn_mfma_f32_16x16x32_bf16(af[m], bfr[n], acc[m][n], 0, 0, 0);
    }
    __syncthreads();
  }

  const long Crow0 = (long)blockIdx.y * 128 + wr * 64;
  const long Ccol0 = (long)blockIdx.x * 128 + wc * 64;
  float*     Cf = (float*)C + (long)blockIdx.z * batchC;
  ushort_t*  Cb = (ushort_t*)C + (long)blockIdx.z * batchC;
#pragma unroll
  for (int m = 0; m < 4; ++m) {
    long r0 = Crow0 + m * 16 + ((lane >> 4) << 2);
#pragma unroll
    for (int n = 0; n < 4; ++n) {
      long cc = Ccol0 + n * 16 + (lane & 15);
#pragma unroll
      for (int j = 0; j < 4; ++j) {
        float val = acc[m][n][j];
        if (OUT_BF16) Cb[(r0 + j) * ldc + cc] = f2bf(val);
        else          Cf[(r0 + j) * ldc + cc] = val;
      }
    }
  }
}

// ---------------------------------------------------------------------------
// 256x256-tile GEMM, BK=64, 512 threads (8 waves, 2Mx4N), 4-phase fine
// interleave with counted vmcnt. C[m,n] = sum_k A[m,k]*B[n,k], bf16, fp32 acc.
// Stripes: A-alpha{0,1} = rows (row%128) in [0,64)/[64,128); B-beta{0,1} =
// rows (row%64) in [0,32)/[32,64). Phase (t,p) stages:
//   p0: Aa1(t+1)L0, Bb1(t+1)L0   p1: Aa1(t+1)L1, Bb1(t+1)L1
//   p2: Aa0(t+2)L0+L1            p3: Bb0(t+2)L0+L1
// Consumption (ds_read): a0,b0 @p0 ; b1 @p1 ; a1 @p2 (regs held after).
// Min issue->consume lag = 4 phases = vmcnt(6) guarantee. Grid 1-D, %8==0.

// phase macros: [reads][stages][barrier][vmcnt][lgkm][mfma][barrier]
#define PH0(cb, ob, t1, WN)                         \
  readA(cb, 0); readB(cb, 0);                       \
  if (t1 >= 0) { stageA(ob, t1, 1, 0); stageB(ob, t1, 1, 0); } \
  BARRIER(); WAITVM(WN); WAITLGKM0(); SCHED0();     \
  mfma16(0, 0);                                     \
  BARRIER(); SCHED0();

#define PH1(cb, ob, t1, WN)                         \
  readB(cb, 1);                                     \
  if (t1 >= 0) { stageA(ob, t1, 1, 1); stageB(ob, t1, 1, 1); } \
  BARRIER(); WAITVM(WN); WAITLGKM0(); SCHED0();     \
  mfma16(0, 1);                                     \
  BARRIER(); SCHED0();

#define PH2(cb, t2, WN)                             \
  readA(cb, 1);                                     \
  if (t2 >= 0) { stageA(cb, t2, 0, 0); stageA(cb, t2, 0, 1); } \
  BARRIER(); WAITVM(WN); WAITLGKM0(); SCHED0();     \
  mfma16(1, 0);                                     \
  BARRIER(); SCHED0();

#define PH3(cb, t2, WN)                             \
  if (t2 >= 0) { stageB(cb, t2, 0, 0); stageB(cb, t2, 0, 1); } \
  BARRIER(); WAITVM(WN); SCHED0();                  \
  mfma16(1, 1);                                     \
  BARRIER(); SCHED0();

template <int OUT_BF16>
__global__ __launch_bounds__(512, 1) void gemm256(
    const ushort_t* __restrict__ A, long lda, long batchA,
    const ushort_t* __restrict__ B, long ldb, long batchB,
    void* __restrict__ C, long ldc, long batchC,
    int K, int tx, int ty) {
  __shared__ ushort_t lds[2][2][16384];   // [dbuf][A=0/B=1][256 rows x 64 cols]

  const int nblk = gridDim.x;
  int f = blockIdx.x;
  f = (f & 7) * (nblk >> 3) + (f >> 3);   // XCD-aware swizzle (nblk % 8 == 0)
  const int txy = tx * ty;
  const int bz = f / txy;
  int r = f - bz * txy;
  const int by = r / tx;
  const int bx = r - by * tx;

  const int tid  = threadIdx.x;
  const int lane = tid & 63;
  const int wid  = tid >> 6;
  const int wr   = wid >> 2;              // 0..1 (M half)
  const int wc   = wid & 3;               // 0..3 (N quarter)
  const int lr   = lane & 15, lg = lane >> 4;

  const ushort_t* Ab = A + (long)bz * batchA + (long)by * 256 * lda;
  const ushort_t* Bb = B + (long)bz * batchB + (long)bx * 256 * ldb;

  f32x4 acc[8][4] = {};
  bf16x8 afr[4][2];   // current M-half fragments
  bf16x8 bfr[4][2];   // full N fragments (held across the K-tile)

  // stage one half-stripe (512 chunks of 16B; 1 load/thread)
  auto stageA = [&](int buf, int kt, int alpha, int half) {
    int c = half * 512 + tid;
    int r7 = c >> 3;                              // 0..127 stripe-row
    int row = ((r7 & 63) | ((r7 & 64) << 1)) + alpha * 64;
    int pch = c & 7;
    int sc = pch ^ (row & 7);                     // source-side swizzle
    GLOAD16(Ab + (long)row * lda + (long)kt * 64 + sc * 8,
            &lds[buf][0][row * 64 + pch * 8]);
  };
  auto stageB = [&](int buf, int kt, int beta, int half) {
    int c = half * 512 + tid;
    int r7 = c >> 3;
    int row = ((r7 & 31) | ((r7 & 96) << 1)) + beta * 32;
    int pch = c & 7;
    int sc = pch ^ (row & 7);
    GLOAD16(Bb + (long)row * ldb + (long)kt * 64 + sc * 8,
            &lds[buf][1][row * 64 + pch * 8]);
  };
  auto readA = [&](int buf, int mh) {
#pragma unroll
    for (int mm = 0; mm < 4; ++mm)
#pragma unroll
      for (int kk = 0; kk < 2; ++kk) {
        int row = wr * 128 + (mh * 4 + mm) * 16 + lr;
        afr[mm][kk] = *(const bf16x8*)((const char*)&lds[buf][0][0] + row * 128 +
                                       (((kk * 4 + lg) ^ (row & 7)) << 4));
      }
  };
  auto readB = [&](int buf, int nh) {
#pragma unroll
    for (int nn = 0; nn < 2; ++nn)
#pragma unroll
      for (int kk = 0; kk < 2; ++kk) {
        int row = wc * 64 + (nh * 2 + nn) * 16 + lr;
        bfr[nh * 2 + nn][kk] = *(const bf16x8*)((const char*)&lds[buf][1][0] + row * 128 +
                                                (((kk * 4 + lg) ^ (row & 7)) << 4));
      }
  };
  auto mfma16 = [&](int mh, int nh) {
    __builtin_amdgcn_s_setprio(1);
#pragma unroll
    for (int kk = 0; kk < 2; ++kk)
#pragma unroll
      for (int mm = 0; mm < 4; ++mm)
#pragma unroll
        for (int nn = 0; nn < 2; ++nn)
          acc[mh * 4 + mm][nh * 2 + nn] = __builtin_amdgcn_mfma_f32_16x16x32_bf16(
              afr[mm][kk], bfr[nh * 2 + nn][kk], acc[mh * 4 + mm][nh * 2 + nn], 0, 0, 0);
    __builtin_amdgcn_s_setprio(0);
  };

  const int nkt = K >> 6;                 // >= 16 for all our shapes
  // prologue: tile0 complete (buf0), tile1 Aa0+Bb0 (buf1) = 12 loads
  stageA(0, 0, 0, 0); stageA(0, 0, 0, 1); stageB(0, 0, 0, 0); stageB(0, 0, 0, 1);
  stageA(0, 0, 1, 0); stageA(0, 0, 1, 1); stageB(0, 0, 1, 0); stageB(0, 0, 1, 1);
  stageA(1, 1, 0, 0); stageA(1, 1, 0, 1); stageB(1, 1, 0, 0); stageB(1, 1, 0, 1);
  WAITVM(4);                              // tile0's 8 loads landed
  BARRIER(); SCHED0();

  for (int t = 0; t < nkt - 2; ++t) {
    const int cb = t & 1, ob = cb ^ 1;
    PH0(cb, ob, t + 1, 6)
    PH1(cb, ob, t + 1, 6)
    PH2(cb, t + 2, 6)
    PH3(cb, t + 2, 6)
  }
  {                                       // t = nkt-2: stage tile nkt-1 only
    const int t = nkt - 2, cb = t & 1, ob = cb ^ 1;
    PH0(cb, ob, t + 1, 6)
    PH1(cb, ob, t + 1, 6)
    PH2(cb, -1, 6)
    PH3(cb, -1, 4)
  }
  {                                       // t = nkt-1: drain
    const int cb = (nkt - 1) & 1, ob = cb ^ 1;
    PH0(cb, ob, -1, 0)
    PH1(cb, ob, -1, 0)
    PH2(cb, -1, 0)
    PH3(cb, -1, 0)
  }

  // epilogue: C/D frag layout col=lane&15, row=(lane>>4)*4+j
  const long Crow0 = (long)by * 256 + wr * 128;
  const long Ccol0 = (long)bx * 256 + wc * 64;
  float*     Cf = (float*)C + (long)bz * batchC;
  ushort_t*  Cb = (ushort_t*)C + (long)bz * batchC;
#pragma unroll
  for (int m = 0; m < 8; ++m) {
    long r0 = Crow0 + m * 16 + ((lane >> 4) << 2);
#pragma unroll
    for (int n = 0; n < 4; ++n) {
      long cc = Ccol0 + n * 16 + (lane & 15);
#pragma unroll
      for (int j = 0; j < 4; ++j) {
        float val = acc[m][n][j];
        if (OUT_BF16) Cb[(r0 + j) * ldc + cc] = f2bf(val);
        else          Cf[(r0 + j) * ldc + cc] = val;
      }
    }
  }
}

// ---------------------------------------------------------------------------
// row softmax over 4096 fp32 scores; write normalized P bf16 to P+row*pstride
__global__ __launch_bounds__(256) void softmax_kernel(float* __restrict__ S,
                                                      ushort_t* __restrict__ P,
                                                      long pstride) {
  float* row = S + (long)blockIdx.x * 4096;
  const int tid = threadIdx.x;
  __shared__ float red[4];

  f32x4 v[4];
#pragma unroll
  for (int i = 0; i < 4; ++i) v[i] = ((const f32x4*)row)[tid + i * 256];

  float m = -1e30f;
#pragma unroll
  for (int i = 0; i < 4; ++i)
#pragma unroll
    for (int j = 0; j < 4; ++j) m = fmaxf(m, v[i][j]);
  for (int o = 32; o; o >>= 1) m = fmaxf(m, __shfl_xor(m, o));
  if ((tid & 63) == 0) red[tid >> 6] = m;
  __syncthreads();
  m = fmaxf(fmaxf(red[0], red[1]), fmaxf(red[2], red[3]));

  float p[16];
  float s = 0.f;
#pragma unroll
  for (int i = 0; i < 4; ++i)
#pragma unroll
    for (int j = 0; j < 4; ++j) {
      float e = __expf(v[i][j] - m);
      p[i * 4 + j] = e;
      s += e;
    }
  for (int o = 32; o; o >>= 1) s += __shfl_xor(s, o);
  __syncthreads();
  if ((tid & 63) == 0) red[tid >> 6] = s;
  __syncthreads();
  s = red[0] + red[1] + red[2] + red[3];
  float inv = 1.0f / s;

  u16x4* prow = (u16x4*)(P + (long)blockIdx.x * pstride);
#pragma unroll
  for (int i = 0; i < 4; ++i) {
    u16x4 o;
    o.x = f2bf(p[i * 4 + 0] * inv);
    o.y = f2bf(p[i * 4 + 1] * inv);
    o.z = f2bf(p[i * 4 + 2] * inv);
    o.w = f2bf(p[i * 4 + 3] * inv);
    prow[tid + i * 256] = o;
  }
}

// row softmax over 4096 bf16 scores, P bf16 written IN PLACE (row-local)
__global__ __launch_bounds__(256) void softmax_bf16_kernel(ushort_t* __restrict__ S) {
  u16x4* row = (u16x4*)(S + (long)blockIdx.x * 4096);
  const int tid = threadIdx.x;
  __shared__ float red[4];

  float v[16];
#pragma unroll
  for (int i = 0; i < 4; ++i) {
    u16x4 h = row[tid + i * 256];
    v[i * 4 + 0] = bf2f(h.x); v[i * 4 + 1] = bf2f(h.y);
    v[i * 4 + 2] = bf2f(h.z); v[i * 4 + 3] = bf2f(h.w);
  }

  float m = -1e30f;
#pragma unroll
  for (int i = 0; i < 16; ++i) m = fmaxf(m, v[i]);
  for (int o = 32; o; o >>= 1) m = fmaxf(m, __shfl_xor(m, o));
  if ((tid & 63) == 0) red[tid >> 6] = m;
  __syncthreads();
  m = fmaxf(fmaxf(red[0], red[1]), fmaxf(red[2], red[3]));

  float s = 0.f;
#pragma unroll
  for (int i = 0; i < 16; ++i) {
    v[i] = __expf(v[i] - m);
    s += v[i];
  }
  for (int o = 32; o; o >>= 1) s += __shfl_xor(s, o);
  __syncthreads();
  if ((tid & 63) == 0) red[tid >> 6] = s;
  __syncthreads();
  s = red[0] + red[1] + red[2] + red[3];
  float inv = 1.0f / s;

#pragma unroll
  for (int i = 0; i < 4; ++i) {
    u16x4 o;
    o.x = f2bf(v[i * 4 + 0] * inv);
    o.y = f2bf(v[i * 4 + 1] * inv);
    o.z = f2bf(v[i * 4 + 2] * inv);
    o.w = f2bf(v[i * 4 + 3] * inv);
    row[tid + i * 256] = o;
  }
}

// ---------------------------------------------------------------------------
extern "C" void kernel_launch(void* const* d_in, const int* in_sizes, int n_in,
                              void* d_out, int out_size, void* d_ws, size_t ws_size,
                              hipStream_t stream) {
  const float* x    = (const float*)d_in[0];   // [4,4096,1024]
  const float* kern = (const float*)d_in[1];   // [3,1024,1024]
  float* out = (float*)d_out;                  // [4,4096,1024]

  char* p = (char*)d_ws;
  ushort_t* xbf = (ushort_t*)p; p += 33554432;         // 16384x1024 bf16
  ushort_t* t   = (ushort_t*)p; p += 33554432;         // 16384x1024 bf16
  ushort_t* vT  = (ushort_t*)p; p += 33554432;         // 4x1024x4096 bf16
  ushort_t* wk  = (ushort_t*)p; p += 2097152;
  ushort_t* wq  = (ushort_t*)p; p += 2097152;
  ushort_t* wvt = (ushort_t*)p; p += 2097152;
  ushort_t* mt  = (ushort_t*)p; p += 2097152;
  size_t fixed = (size_t)(p - (char*)d_ws);            // 104 MiB

  cast_bf16_kernel<<<8192, 256, 0, stream>>>(x, xbf);
  prep_weights_kernel<<<4096, 256, 0, stream>>>(kern, wk, wq, wvt);
  // Mt[d',d] = sum_e Wk[d',e] * Wq_s[d,e]  (tiny; 128^2 kernel)
  gemm_bt<1><<<dim3(8, 8, 1), 256, 0, stream>>>(wk, 1024, 0, wq, 1024, 0, mt, 1024, 0, 1024);

  const size_t need4 = fixed + 4ull * 33554432;        // 4 bf16 S/P buffers
  const size_t need2 = fixed + 2ull * 33554432;        // 2 bf16 S/P buffers

  if (ws_size >= need2) {
    ushort_t* Sb = (ushort_t*)p;                       // 2 or 4 x (4096x4096 bf16)

    // t[q,d'] = sum_d x[q,d] * Mt[d',d]      grid 4x64 = 256
    gemm256<1><<<dim3(256), dim3(512), 0, stream>>>(xbf, 1024, 0, mt, 1024, 0,
                                                    t, 1024, 0, 1024, 4, 64);
    // vT[b][e,s] = sum_d WvT[e,d] * x_b[s,d]  grid 16x4x4 = 256
    gemm256<1><<<dim3(256), dim3(512), 0, stream>>>(wvt, 1024, 0,
                                                    xbf, 1024, 4194304,
                                                    vT, 4096, 4194304, 1024, 16, 4);

    const int nb_at_once = (ws_size >= need4) ? 4 : 2;
    for (int b0 = 0; b0 < 4; b0 += nb_at_once) {
      for (int b = b0; b < b0 + nb_at_once; ++b) {
        // S_b[q,k] = sum_d' t_b[q,d'] x_b[k,d']  (bf16 out)  grid 16x16 = 256
        gemm256<1><<<dim3(256), dim3(512), 0, stream>>>(
            t + (long)b * 4194304, 1024, 0,
            xbf + (long)b * 4194304, 1024, 0,
            Sb + (long)(b - b0) * 16777216, 4096, 0, 1024, 16, 16);
      }
      // softmax all staged rows in one dispatch (in-place bf16 P)
      softmax_bf16_kernel<<<4096 * nb_at_once, 256, 0, stream>>>(Sb);
      // out[b][q,e] = sum_k P_b[q,k] vT_b[e,k]  grid 4x16xnb
      gemm256<0><<<dim3(4 * 16 * nb_at_once), dim3(512), 0, stream>>>(
          Sb, 4096, 16777216,
          vT + (long)b0 * 4194304, 4096, 4194304,
          out + (long)b0 * 4194304, 1024, 4194304, 4096, 4, 16);
    }
  } else {
    // -------- low-ws fallback (chunked, in-place packed P) --------
    float* Sbuf = (float*)p;
    long CR = 4096;
    while (CR > 256 && fixed + (size_t)CR * 4096 * 4 > ws_size) CR >>= 1;

    gemm_bt<1><<<dim3(8, 128, 1), 256, 0, stream>>>(xbf, 1024, 0, mt, 1024, 0, t, 1024, 0, 1024);
    gemm_bt<1><<<dim3(32, 8, 4), 256, 0, stream>>>(wvt, 1024, 0,
                                                   xbf, 1024, 4194304,
                                                   vT, 4096, 4194304, 1024);
    for (int b = 0; b < 4; ++b) {
      const ushort_t* xb  = xbf + (long)b * 4194304;
      const ushort_t* vTb = vT  + (long)b * 4194304;
      for (long c0 = 0; c0 < 4096; c0 += CR) {
        const ushort_t* tb = t + ((long)b * 4096 + c0) * 1024;
        gemm_bt<0><<<dim3(32, CR / 128, 1), 256, 0, stream>>>(tb, 1024, 0, xb, 1024, 0,
                                                              Sbuf, 4096, 0, 1024);
        softmax_kernel<<<CR, 256, 0, stream>>>(Sbuf, (ushort_t*)Sbuf, 8192);
        gemm_bt<0><<<dim3(8, CR / 128, 1), 256, 0, stream>>>((const ushort_t*)Sbuf, 8192, 0,
                                                             vTb, 4096, 0,
                                                             out + ((long)b * 4096 + c0) * 1024, 1024, 0,
                                                             4096);
      }
    }
  }
}

// Round 5
// 390.978 us; speedup vs baseline: 1.8572x; 1.0542x over previous
//
#include <hip/hip_runtime.h>

// ---------------------------------------------------------------------------
// Self-attention, B=4 S=4096 D=DOUT=1024, fp32 in/out.
// scores = x (Wq Wk^T / 32) x^T  -> t = x*M ; S = t x^T  (accuracy trick)
// Round 5: gemm256 phases = M-quarter x full-N (reads 12/4/4/4), compiler-
// counted lgkm waits (no manual lgkmcnt(0)), ONE barrier per phase, single
// vmcnt(4) per K-tile at PH3. S-GEMMs batched into one dispatch.
// ---------------------------------------------------------------------------

typedef unsigned short ushort_t;
typedef __attribute__((ext_vector_type(8))) short     bf16x8;
typedef __attribute__((ext_vector_type(4))) float     f32x4;
typedef __attribute__((ext_vector_type(4))) unsigned int u32x4;
typedef __attribute__((ext_vector_type(4))) unsigned short u16x4;

__device__ __forceinline__ unsigned short f2bf(float f) {
  unsigned u = __float_as_uint(f);
  return (unsigned short)((u + 0x7FFFu + ((u >> 16) & 1u)) >> 16);
}
__device__ __forceinline__ float bf2f(unsigned short h) {
  return __uint_as_float((unsigned)h << 16);
}

#define GLOAD16(gsrc, ldst)                                                        \
  __builtin_amdgcn_global_load_lds(                                                \
      (const __attribute__((address_space(1))) void*)(gsrc),                       \
      (__attribute__((address_space(3))) void*)(ldst), 16, 0, 0)
#define WAITVM(N) asm volatile("s_waitcnt vmcnt(" #N ")" ::: "memory")
#define SCHED0()  __builtin_amdgcn_sched_barrier(0)
#define BARRIER() __builtin_amdgcn_s_barrier()

// ---------------------------------------------------------------------------
__global__ __launch_bounds__(256) void cast_bf16_kernel(const float* __restrict__ in,
                                                        ushort_t* __restrict__ out) {
  long i = (long)blockIdx.x * 256 + threadIdx.x;
  const f32x4* p = (const f32x4*)(in + i * 8);
  f32x4 a = p[0], b = p[1];
  u32x4 o;
  o.x = (unsigned)f2bf(a[0]) | ((unsigned)f2bf(a[1]) << 16);
  o.y = (unsigned)f2bf(a[2]) | ((unsigned)f2bf(a[3]) << 16);
  o.z = (unsigned)f2bf(b[0]) | ((unsigned)f2bf(b[1]) << 16);
  o.w = (unsigned)f2bf(b[2]) | ((unsigned)f2bf(b[3]) << 16);
  ((u32x4*)out)[i] = o;
}

__global__ __launch_bounds__(256) void prep_weights_kernel(const float* __restrict__ kern,
                                                           ushort_t* __restrict__ wk,
                                                           ushort_t* __restrict__ wq,
                                                           ushort_t* __restrict__ wvt) {
  int idx = blockIdx.x * 256 + threadIdx.x;
  wk[idx] = f2bf(kern[idx]);
  wq[idx] = f2bf(kern[1048576 + idx] * 0.03125f);
  int e = idx >> 10, d = idx & 1023;
  wvt[idx] = f2bf(kern[2097152 + d * 1024 + e]);
}

// ---------------------------------------------------------------------------
// 128^2-tile GEMM (kept for the tiny Mt GEMM + low-ws fallback)
template <int OUT_BF16>
__global__ __launch_bounds__(256) void gemm_bt(const ushort_t* __restrict__ A, long lda, long batchA,
                                               const ushort_t* __restrict__ B, long ldb, long batchB,
                                               void* __restrict__ C, long ldc, long batchC,
                                               int K) {
  __shared__ ushort_t lA[128 * 64];
  __shared__ ushort_t lB[128 * 64];

  const int tid  = threadIdx.x;
  const int lane = tid & 63;
  const int wid  = tid >> 6;
  const int wr   = wid >> 1;
  const int wc   = wid & 1;

  const ushort_t* Ab = A + (long)blockIdx.z * batchA + (long)blockIdx.y * 128 * lda;
  const ushort_t* Bb = B + (long)blockIdx.z * batchB + (long)blockIdx.x * 128 * ldb;

  f32x4 acc[4][4] = {};

  const int nkt = K >> 6;
  for (int kt = 0; kt < nkt; ++kt) {
#pragma unroll
    for (int i = 0; i < 4; ++i) {
      int c = tid + i * 256;
      int row = c >> 3, p = c & 7;
      int sc = p ^ (row & 7);
      GLOAD16(Ab + (long)row * lda + kt * 64 + sc * 8, &lA[c * 8]);
    }
#pragma unroll
    for (int i = 0; i < 4; ++i) {
      int c = tid + i * 256;
      int row = c >> 3, p = c & 7;
      int sc = p ^ (row & 7);
      GLOAD16(Bb + (long)row * ldb + kt * 64 + sc * 8, &lB[c * 8]);
    }
    __syncthreads();

    const int lr = lane & 15, lg = lane >> 4;
#pragma unroll
    for (int kk = 0; kk < 2; ++kk) {
      bf16x8 af[4], bfr[4];
#pragma unroll
      for (int m = 0; m < 4; ++m) {
        int row = wr * 64 + m * 16 + lr;
        int cidx = kk * 4 + lg;
        af[m] = *(const bf16x8*)((const char*)lA + row * 128 + ((cidx ^ (row & 7)) << 4));
      }
#pragma unroll
      for (int n = 0; n < 4; ++n) {
        int row = wc * 64 + n * 16 + lr;
        int cidx = kk * 4 + lg;
        bfr[n] = *(const bf16x8*)((const char*)lB + row * 128 + ((cidx ^ (row & 7)) << 4));
      }
#pragma unroll
      for (int m = 0; m < 4; ++m)
#pragma unroll
        for (int n = 0; n < 4; ++n)
          acc[m][n] = __builtin_amdgcn_mfma_f32_16x16x32_bf16(af[m], bfr[n], acc[m][n], 0, 0, 0);
    }
    __syncthreads();
  }

  const long Crow0 = (long)blockIdx.y * 128 + wr * 64;
  const long Ccol0 = (long)blockIdx.x * 128 + wc * 64;
  float*     Cf = (float*)C + (long)blockIdx.z * batchC;
  ushort_t*  Cb = (ushort_t*)C + (long)blockIdx.z * batchC;
#pragma unroll
  for (int m = 0; m < 4; ++m) {
    long r0 = Crow0 + m * 16 + ((lane >> 4) << 2);
#pragma unroll
    for (int n = 0; n < 4; ++n) {
      long cc = Ccol0 + n * 16 + (lane & 15);
#pragma unroll
      for (int j = 0; j < 4; ++j) {
        float val = acc[m][n][j];
        if (OUT_BF16) Cb[(r0 + j) * ldc + cc] = f2bf(val);
        else          Cf[(r0 + j) * ldc + cc] = val;
      }
    }
  }
}

// ---------------------------------------------------------------------------
// 256x256-tile GEMM, BK=64, 512 threads (8 waves, 2Mx4N).
// Phase q (q=0..3) = M-quarter q x full N: reads A-quarter (4 b128; B full 8
// b128 at PH0 only, held per K-tile), issues 2 half-stripe gload_lds, 16 MFMA,
// ONE barrier. Single vmcnt(4) per K-tile at PH3 (tail vmcnt(0)).
// Stage schedule per K-tile t: PH0/PH1 stage tile t+1 second halves (Aa1,Bb1
// into buf ob); PH2/PH3 stage tile t+2 first halves (Aa0,Bb0 into buf cb).
// Ledger: overwrite-safe (staged region last ds_read >=2 end-barriers prior,
// reads retired via consuming MFMA's counted lgkm waits); landing-safe
// (vmcnt(4)@PH3 leaves exactly PH2/PH3(t) loads in flight => tile t+1 fully
// landed before its PH0 reads). Grid 1-D (tx*ty*bz, %8==0), XCD-swizzled.

#define PH0(cb, ob, t1, STG)                                     \
  readAq(cb, 0); readB(cb);                                      \
  if (STG) { stageA(ob, t1, 1, 0); stageB(ob, t1, 1, 0); }       \
  mfma16q(0); BARRIER(); SCHED0();

#define PH1(cb, ob, t1, STG)                                     \
  readAq(cb, 1);                                                 \
  if (STG) { stageA(ob, t1, 1, 1); stageB(ob, t1, 1, 1); }       \
  mfma16q(1); BARRIER(); SCHED0();

#define PH2(cb, t2, STG)                                         \
  readAq(cb, 2);                                                 \
  if (STG) { stageA(cb, t2, 0, 0); stageA(cb, t2, 0, 1); }       \
  mfma16q(2); BARRIER(); SCHED0();

#define PH3_W4(cb, t2)                                           \
  readAq(cb, 3);                                                 \
  stageB(cb, t2, 0, 0); stageB(cb, t2, 0, 1);                    \
  WAITVM(4); mfma16q(3); BARRIER(); SCHED0();

template <int OUT_BF16>
__global__ __launch_bounds__(512, 1) void gemm256(
    const ushort_t* __restrict__ A, long lda, long batchA,
    const ushort_t* __restrict__ B, long ldb, long batchB,
    void* __restrict__ C, long ldc, long batchC,
    int K, int tx, int ty) {
  __shared__ ushort_t lds[2][2][16384];   // [dbuf][A=0/B=1][256 rows x 64 cols]

  const int nblk = gridDim.x;
  int f = blockIdx.x;
  f = (f & 7) * (nblk >> 3) + (f >> 3);   // XCD-aware swizzle (nblk % 8 == 0)
  const int txy = tx * ty;
  const int bz = f / txy;
  int r = f - bz * txy;
  const int by = r / tx;
  const int bx = r - by * tx;

  const int tid  = threadIdx.x;
  const int lane = tid & 63;
  const int wid  = tid >> 6;
  const int wr   = wid >> 2;              // 0..1 (M half)
  const int wc   = wid & 3;               // 0..3 (N quarter)
  const int lr   = lane & 15, lg = lane >> 4;

  const ushort_t* Ab = A + (long)bz * batchA + (long)by * 256 * lda;
  const ushort_t* Bb = B + (long)bz * batchB + (long)bx * 256 * ldb;

  f32x4 acc[8][4] = {};
  bf16x8 afr[2][2];   // current M-quarter fragments (2m x 2kk)
  bf16x8 bfr[4][2];   // full-N fragments (held across the K-tile)

  // stage one half-stripe (512 chunks of 16B; 1 load/thread)
  auto stageA = [&](int buf, int kt, int alpha, int half) {
    int c = half * 512 + tid;
    int r7 = c >> 3;                              // 0..127 stripe-row
    int row = ((r7 & 63) | ((r7 & 64) << 1)) + alpha * 64;
    int pch = c & 7;
    int sc = pch ^ (row & 7);                     // source-side swizzle
    GLOAD16(Ab + (long)row * lda + (long)kt * 64 + sc * 8,
            &lds[buf][0][row * 64 + pch * 8]);
  };
  auto stageB = [&](int buf, int kt, int beta, int half) {
    int c = half * 512 + tid;
    int r7 = c >> 3;
    int row = ((r7 & 31) | ((r7 & 96) << 1)) + beta * 32;
    int pch = c & 7;
    int sc = pch ^ (row & 7);
    GLOAD16(Bb + (long)row * ldb + (long)kt * 64 + sc * 8,
            &lds[buf][1][row * 64 + pch * 8]);
  };
  auto readAq = [&](int buf, int q) {
#pragma unroll
    for (int mm = 0; mm < 2; ++mm)
#pragma unroll
      for (int kk = 0; kk < 2; ++kk) {
        int row = wr * 128 + (q * 2 + mm) * 16 + lr;
        afr[mm][kk] = *(const bf16x8*)((const char*)&lds[buf][0][0] + row * 128 +
                                       (((kk * 4 + lg) ^ (row & 7)) << 4));
      }
  };
  auto readB = [&](int buf) {
#pragma unroll
    for (int nn = 0; nn < 4; ++nn)
#pragma unroll
      for (int kk = 0; kk < 2; ++kk) {
        int row = wc * 64 + nn * 16 + lr;
        bfr[nn][kk] = *(const bf16x8*)((const char*)&lds[buf][1][0] + row * 128 +
                                       (((kk * 4 + lg) ^ (row & 7)) << 4));
      }
  };
  auto mfma16q = [&](int q) {
    __builtin_amdgcn_s_setprio(1);
#pragma unroll
    for (int kk = 0; kk < 2; ++kk)
#pragma unroll
      for (int nn = 0; nn < 4; ++nn)
#pragma unroll
        for (int mm = 0; mm < 2; ++mm)
          acc[q * 2 + mm][nn] = __builtin_amdgcn_mfma_f32_16x16x32_bf16(
              afr[mm][kk], bfr[nn][kk], acc[q * 2 + mm][nn], 0, 0, 0);
    __builtin_amdgcn_s_setprio(0);
  };

  const int nkt = K >> 6;                 // >= 16 for all our shapes
  // prologue: tile0 complete (buf0), tile1 first halves Aa0+Bb0 (buf1)
  stageA(0, 0, 0, 0); stageA(0, 0, 0, 1); stageB(0, 0, 0, 0); stageB(0, 0, 0, 1);
  stageA(0, 0, 1, 0); stageA(0, 0, 1, 1); stageB(0, 0, 1, 0); stageB(0, 0, 1, 1);
  stageA(1, 1, 0, 0); stageA(1, 1, 0, 1); stageB(1, 1, 0, 0); stageB(1, 1, 0, 1);
  WAITVM(4);                              // tile0's 8 loads landed
  BARRIER(); SCHED0();

  for (int t = 0; t < nkt - 2; ++t) {
    const int cb = t & 1, ob = cb ^ 1;
    PH0(cb, ob, t + 1, 1)
    PH1(cb, ob, t + 1, 1)
    PH2(cb, t + 2, 1)
    PH3_W4(cb, t + 2)
  }
  {                                       // t = nkt-2: stage tile nkt-1 h2 only
    const int t = nkt - 2, cb = t & 1, ob = cb ^ 1;
    PH0(cb, ob, t + 1, 1)
    PH1(cb, ob, t + 1, 1)
    PH2(cb, 0, 0)
    readAq(cb, 3);
    WAITVM(0);                            // drain: tile nkt-1 fully landed
    mfma16q(3); BARRIER(); SCHED0();
  }
  {                                       // t = nkt-1: pure compute
    const int cb = (nkt - 1) & 1, ob = cb ^ 1;
    PH0(cb, ob, 0, 0)
    PH1(cb, ob, 0, 0)
    PH2(cb, 0, 0)
    readAq(cb, 3);
    mfma16q(3);
  }

  // epilogue: C/D frag layout col=lane&15, row=(lane>>4)*4+j
  const long Crow0 = (long)by * 256 + wr * 128;
  const long Ccol0 = (long)bx * 256 + wc * 64;
  float*     Cf = (float*)C + (long)bz * batchC;
  ushort_t*  Cb = (ushort_t*)C + (long)bz * batchC;
#pragma unroll
  for (int m = 0; m < 8; ++m) {
    long r0 = Crow0 + m * 16 + ((lane >> 4) << 2);
#pragma unroll
    for (int n = 0; n < 4; ++n) {
      long cc = Ccol0 + n * 16 + (lane & 15);
#pragma unroll
      for (int j = 0; j < 4; ++j) {
        float val = acc[m][n][j];
        if (OUT_BF16) Cb[(r0 + j) * ldc + cc] = f2bf(val);
        else          Cf[(r0 + j) * ldc + cc] = val;
      }
    }
  }
}

// ---------------------------------------------------------------------------
// row softmax over 4096 fp32 scores; write normalized P bf16 to P+row*pstride
__global__ __launch_bounds__(256) void softmax_kernel(float* __restrict__ S,
                                                      ushort_t* __restrict__ P,
                                                      long pstride) {
  float* row = S + (long)blockIdx.x * 4096;
  const int tid = threadIdx.x;
  __shared__ float red[4];

  f32x4 v[4];
#pragma unroll
  for (int i = 0; i < 4; ++i) v[i] = ((const f32x4*)row)[tid + i * 256];

  float m = -1e30f;
#pragma unroll
  for (int i = 0; i < 4; ++i)
#pragma unroll
    for (int j = 0; j < 4; ++j) m = fmaxf(m, v[i][j]);
  for (int o = 32; o; o >>= 1) m = fmaxf(m, __shfl_xor(m, o));
  if ((tid & 63) == 0) red[tid >> 6] = m;
  __syncthreads();
  m = fmaxf(fmaxf(red[0], red[1]), fmaxf(red[2], red[3]));

  float p[16];
  float s = 0.f;
#pragma unroll
  for (int i = 0; i < 4; ++i)
#pragma unroll
    for (int j = 0; j < 4; ++j) {
      float e = __expf(v[i][j] - m);
      p[i * 4 + j] = e;
      s += e;
    }
  for (int o = 32; o; o >>= 1) s += __shfl_xor(s, o);
  __syncthreads();
  if ((tid & 63) == 0) red[tid >> 6] = s;
  __syncthreads();
  s = red[0] + red[1] + red[2] + red[3];
  float inv = 1.0f / s;

  u16x4* prow = (u16x4*)(P + (long)blockIdx.x * pstride);
#pragma unroll
  for (int i = 0; i < 4; ++i) {
    u16x4 o;
    o.x = f2bf(p[i * 4 + 0] * inv);
    o.y = f2bf(p[i * 4 + 1] * inv);
    o.z = f2bf(p[i * 4 + 2] * inv);
    o.w = f2bf(p[i * 4 + 3] * inv);
    prow[tid + i * 256] = o;
  }
}

// row softmax over 4096 bf16 scores, P bf16 written IN PLACE (row-local)
__global__ __launch_bounds__(256) void softmax_bf16_kernel(ushort_t* __restrict__ S) {
  u16x4* row = (u16x4*)(S + (long)blockIdx.x * 4096);
  const int tid = threadIdx.x;
  __shared__ float red[4];

  float v[16];
#pragma unroll
  for (int i = 0; i < 4; ++i) {
    u16x4 h = row[tid + i * 256];
    v[i * 4 + 0] = bf2f(h.x); v[i * 4 + 1] = bf2f(h.y);
    v[i * 4 + 2] = bf2f(h.z); v[i * 4 + 3] = bf2f(h.w);
  }

  float m = -1e30f;
#pragma unroll
  for (int i = 0; i < 16; ++i) m = fmaxf(m, v[i]);
  for (int o = 32; o; o >>= 1) m = fmaxf(m, __shfl_xor(m, o));
  if ((tid & 63) == 0) red[tid >> 6] = m;
  __syncthreads();
  m = fmaxf(fmaxf(red[0], red[1]), fmaxf(red[2], red[3]));

  float s = 0.f;
#pragma unroll
  for (int i = 0; i < 16; ++i) {
    v[i] = __expf(v[i] - m);
    s += v[i];
  }
  for (int o = 32; o; o >>= 1) s += __shfl_xor(s, o);
  __syncthreads();
  if ((tid & 63) == 0) red[tid >> 6] = s;
  __syncthreads();
  s = red[0] + red[1] + red[2] + red[3];
  float inv = 1.0f / s;

#pragma unroll
  for (int i = 0; i < 4; ++i) {
    u16x4 o;
    o.x = f2bf(v[i * 4 + 0] * inv);
    o.y = f2bf(v[i * 4 + 1] * inv);
    o.z = f2bf(v[i * 4 + 2] * inv);
    o.w = f2bf(v[i * 4 + 3] * inv);
    row[tid + i * 256] = o;
  }
}

// ---------------------------------------------------------------------------
extern "C" void kernel_launch(void* const* d_in, const int* in_sizes, int n_in,
                              void* d_out, int out_size, void* d_ws, size_t ws_size,
                              hipStream_t stream) {
  const float* x    = (const float*)d_in[0];   // [4,4096,1024]
  const float* kern = (const float*)d_in[1];   // [3,1024,1024]
  float* out = (float*)d_out;                  // [4,4096,1024]

  char* p = (char*)d_ws;
  ushort_t* xbf = (ushort_t*)p; p += 33554432;         // 16384x1024 bf16
  ushort_t* t   = (ushort_t*)p; p += 33554432;         // 16384x1024 bf16
  ushort_t* vT  = (ushort_t*)p; p += 33554432;         // 4x1024x4096 bf16
  ushort_t* wk  = (ushort_t*)p; p += 2097152;
  ushort_t* wq  = (ushort_t*)p; p += 2097152;
  ushort_t* wvt = (ushort_t*)p; p += 2097152;
  ushort_t* mt  = (ushort_t*)p; p += 2097152;
  size_t fixed = (size_t)(p - (char*)d_ws);            // 104 MiB

  cast_bf16_kernel<<<8192, 256, 0, stream>>>(x, xbf);
  prep_weights_kernel<<<4096, 256, 0, stream>>>(kern, wk, wq, wvt);
  // Mt[d',d] = sum_e Wk[d',e] * Wq_s[d,e]  (tiny; 128^2 kernel)
  gemm_bt<1><<<dim3(8, 8, 1), 256, 0, stream>>>(wk, 1024, 0, wq, 1024, 0, mt, 1024, 0, 1024);

  const size_t need4 = fixed + 4ull * 33554432;        // 4 bf16 S/P buffers
  const size_t need2 = fixed + 2ull * 33554432;        // 2 bf16 S/P buffers

  if (ws_size >= need2) {
    ushort_t* Sb = (ushort_t*)p;                       // 2 or 4 x (4096x4096 bf16)

    // t[q,d'] = sum_d x[q,d] * Mt[d',d]      grid 4x64 = 256
    gemm256<1><<<dim3(256), dim3(512), 0, stream>>>(xbf, 1024, 0, mt, 1024, 0,
                                                    t, 1024, 0, 1024, 4, 64);
    // vT[b][e,s] = sum_d WvT[e,d] * x_b[s,d]  grid 16x4x4 = 256
    gemm256<1><<<dim3(256), dim3(512), 0, stream>>>(wvt, 1024, 0,
                                                    xbf, 1024, 4194304,
                                                    vT, 4096, 4194304, 1024, 16, 4);

    const int nb_at_once = (ws_size >= need4) ? 4 : 2;
    for (int b0 = 0; b0 < 4; b0 += nb_at_once) {
      // S_b[q,k] = sum_d' t_b[q,d'] x_b[k,d']  (bf16 out), batched dispatch
      gemm256<1><<<dim3(256 * nb_at_once), dim3(512), 0, stream>>>(
          t + (long)b0 * 4194304, 1024, 4194304,
          xbf + (long)b0 * 4194304, 1024, 4194304,
          Sb, 4096, 16777216, 1024, 16, 16);
      // softmax all staged rows in one dispatch (in-place bf16 P)
      softmax_bf16_kernel<<<4096 * nb_at_once, 256, 0, stream>>>(Sb);
      // out[b][q,e] = sum_k P_b[q,k] vT_b[e,k]
      gemm256<0><<<dim3(4 * 16 * nb_at_once), dim3(512), 0, stream>>>(
          Sb, 4096, 16777216,
          vT + (long)b0 * 4194304, 4096, 4194304,
          out + (long)b0 * 4194304, 1024, 4194304, 4096, 4, 16);
    }
  } else {
    // -------- low-ws fallback (chunked, in-place packed P) --------
    float* Sbuf = (float*)p;
    long CR = 4096;
    while (CR > 256 && fixed + (size_t)CR * 4096 * 4 > ws_size) CR >>= 1;

    gemm_bt<1><<<dim3(8, 128, 1), 256, 0, stream>>>(xbf, 1024, 0, mt, 1024, 0, t, 1024, 0, 1024);
    gemm_bt<1><<<dim3(32, 8, 4), 256, 0, stream>>>(wvt, 1024, 0,
                                                   xbf, 1024, 4194304,
                                                   vT, 4096, 4194304, 1024);
    for (int b = 0; b < 4; ++b) {
      const ushort_t* xb  = xbf + (long)b * 4194304;
      const ushort_t* vTb = vT  + (long)b * 4194304;
      for (long c0 = 0; c0 < 4096; c0 += CR) {
        const ushort_t* tb = t + ((long)b * 4096 + c0) * 1024;
        gemm_bt<0><<<dim3(32, CR / 128, 1), 256, 0, stream>>>(tb, 1024, 0, xb, 1024, 0,
                                                              Sbuf, 4096, 0, 1024);
        softmax_kernel<<<CR, 256, 0, stream>>>(Sbuf, (ushort_t*)Sbuf, 8192);
        gemm_bt<0><<<dim3(8, CR / 128, 1), 256, 0, stream>>>((const ushort_t*)Sbuf, 8192, 0,
                                                             vTb, 4096, 0,
                                                             out + ((long)b * 4096 + c0) * 1024, 1024, 0,
                                                             4096);
      }
    }
  }
}

// Round 6
// 385.229 us; speedup vs baseline: 1.8849x; 1.0149x over previous
//
#include <hip/hip_runtime.h>

// ---------------------------------------------------------------------------
// Self-attention, B=4 S=4096 D=DOUT=1024, fp32 in/out.
// scores = x (Wq Wk^T / 32) x^T  -> t = x*M ; S = t x^T  (accuracy trick)
// Round 6: gemm256 keeps round-5's 4-phase/1-barrier schedule but with ALL
// loop addressing hoisted: ds_read = 4 lane-base VGPRs + imm offsets;
// stage src = 2 pointer VGPRs (+128B/tile) + 8 uniform SGPR offsets;
// stage dst = 2 per-thread consts + compile-time deltas + buf bit.
// ---------------------------------------------------------------------------

typedef unsigned short ushort_t;
typedef __attribute__((ext_vector_type(8))) short     bf16x8;
typedef __attribute__((ext_vector_type(4))) float     f32x4;
typedef __attribute__((ext_vector_type(4))) unsigned int u32x4;
typedef __attribute__((ext_vector_type(4))) unsigned short u16x4;

__device__ __forceinline__ unsigned short f2bf(float f) {
  unsigned u = __float_as_uint(f);
  return (unsigned short)((u + 0x7FFFu + ((u >> 16) & 1u)) >> 16);
}
__device__ __forceinline__ float bf2f(unsigned short h) {
  return __uint_as_float((unsigned)h << 16);
}

#define GLOAD16(gsrc, ldst)                                                        \
  __builtin_amdgcn_global_load_lds(                                                \
      (const __attribute__((address_space(1))) void*)(gsrc),                       \
      (__attribute__((address_space(3))) void*)(ldst), 16, 0, 0)
#define WAITVM(N) asm volatile("s_waitcnt vmcnt(" #N ")" ::: "memory")
#define SCHED0()  __builtin_amdgcn_sched_barrier(0)
#define BARRIER() __builtin_amdgcn_s_barrier()

// ---------------------------------------------------------------------------
__global__ __launch_bounds__(256) void cast_bf16_kernel(const float* __restrict__ in,
                                                        ushort_t* __restrict__ out) {
  long i = (long)blockIdx.x * 256 + threadIdx.x;
  const f32x4* p = (const f32x4*)(in + i * 8);
  f32x4 a = p[0], b = p[1];
  u32x4 o;
  o.x = (unsigned)f2bf(a[0]) | ((unsigned)f2bf(a[1]) << 16);
  o.y = (unsigned)f2bf(a[2]) | ((unsigned)f2bf(a[3]) << 16);
  o.z = (unsigned)f2bf(b[0]) | ((unsigned)f2bf(b[1]) << 16);
  o.w = (unsigned)f2bf(b[2]) | ((unsigned)f2bf(b[3]) << 16);
  ((u32x4*)out)[i] = o;
}

__global__ __launch_bounds__(256) void prep_weights_kernel(const float* __restrict__ kern,
                                                           ushort_t* __restrict__ wk,
                                                           ushort_t* __restrict__ wq,
                                                           ushort_t* __restrict__ wvt) {
  int idx = blockIdx.x * 256 + threadIdx.x;
  wk[idx] = f2bf(kern[idx]);
  wq[idx] = f2bf(kern[1048576 + idx] * 0.03125f);
  int e = idx >> 10, d = idx & 1023;
  wvt[idx] = f2bf(kern[2097152 + d * 1024 + e]);
}

// ---------------------------------------------------------------------------
// 128^2-tile GEMM (kept for the tiny Mt GEMM + low-ws fallback)
template <int OUT_BF16>
__global__ __launch_bounds__(256) void gemm_bt(const ushort_t* __restrict__ A, long lda, long batchA,
                                               const ushort_t* __restrict__ B, long ldb, long batchB,
                                               void* __restrict__ C, long ldc, long batchC,
                                               int K) {
  __shared__ ushort_t lA[128 * 64];
  __shared__ ushort_t lB[128 * 64];

  const int tid  = threadIdx.x;
  const int lane = tid & 63;
  const int wid  = tid >> 6;
  const int wr   = wid >> 1;
  const int wc   = wid & 1;

  const ushort_t* Ab = A + (long)blockIdx.z * batchA + (long)blockIdx.y * 128 * lda;
  const ushort_t* Bb = B + (long)blockIdx.z * batchB + (long)blockIdx.x * 128 * ldb;

  f32x4 acc[4][4] = {};

  const int nkt = K >> 6;
  for (int kt = 0; kt < nkt; ++kt) {
#pragma unroll
    for (int i = 0; i < 4; ++i) {
      int c = tid + i * 256;
      int row = c >> 3, p = c & 7;
      int sc = p ^ (row & 7);
      GLOAD16(Ab + (long)row * lda + kt * 64 + sc * 8, &lA[c * 8]);
    }
#pragma unroll
    for (int i = 0; i < 4; ++i) {
      int c = tid + i * 256;
      int row = c >> 3, p = c & 7;
      int sc = p ^ (row & 7);
      GLOAD16(Bb + (long)row * ldb + kt * 64 + sc * 8, &lB[c * 8]);
    }
    __syncthreads();

    const int lr = lane & 15, lg = lane >> 4;
#pragma unroll
    for (int kk = 0; kk < 2; ++kk) {
      bf16x8 af[4], bfr[4];
#pragma unroll
      for (int m = 0; m < 4; ++m) {
        int row = wr * 64 + m * 16 + lr;
        int cidx = kk * 4 + lg;
        af[m] = *(const bf16x8*)((const char*)lA + row * 128 + ((cidx ^ (row & 7)) << 4));
      }
#pragma unroll
      for (int n = 0; n < 4; ++n) {
        int row = wc * 64 + n * 16 + lr;
        int cidx = kk * 4 + lg;
        bfr[n] = *(const bf16x8*)((const char*)lB + row * 128 + ((cidx ^ (row & 7)) << 4));
      }
#pragma unroll
      for (int m = 0; m < 4; ++m)
#pragma unroll
        for (int n = 0; n < 4; ++n)
          acc[m][n] = __builtin_amdgcn_mfma_f32_16x16x32_bf16(af[m], bfr[n], acc[m][n], 0, 0, 0);
    }
    __syncthreads();
  }

  const long Crow0 = (long)blockIdx.y * 128 + wr * 64;
  const long Ccol0 = (long)blockIdx.x * 128 + wc * 64;
  float*     Cf = (float*)C + (long)blockIdx.z * batchC;
  ushort_t*  Cb = (ushort_t*)C + (long)blockIdx.z * batchC;
#pragma unroll
  for (int m = 0; m < 4; ++m) {
    long r0 = Crow0 + m * 16 + ((lane >> 4) << 2);
#pragma unroll
    for (int n = 0; n < 4; ++n) {
      long cc = Ccol0 + n * 16 + (lane & 15);
#pragma unroll
      for (int j = 0; j < 4; ++j) {
        float val = acc[m][n][j];
        if (OUT_BF16) Cb[(r0 + j) * ldc + cc] = f2bf(val);
        else          Cf[(r0 + j) * ldc + cc] = val;
      }
    }
  }
}

// ---------------------------------------------------------------------------
// 256x256-tile GEMM, BK=64, 512 threads (8 waves, 2Mx4N), 4-phase/K-tile,
// ONE barrier per phase, vmcnt(4) once per K-tile at PH3.
// All addressing hoisted (see header comment). Schedule/ledger identical to
// round 5 (verified passing): PH0/PH1 stage tile t+1 2nd halves -> ob;
// PH2/PH3 stage tile t+2 1st halves -> cb; reads of a staged region always
// retired >= 1 end-barrier before its overwrite; vmcnt(4)@PH3 + barrier
// guarantees tile t+1 fully landed before its PH0 reads.
template <int OUT_BF16>
__global__ __launch_bounds__(512, 1) void gemm256(
    const ushort_t* __restrict__ A, long lda, long batchA,
    const ushort_t* __restrict__ B, long ldb, long batchB,
    void* __restrict__ C, long ldc, long batchC,
    int K, int tx, int ty) {
  __shared__ ushort_t lds[2][2][16384];   // [dbuf][A=0/B=1][256 rows x 64 cols]

  const int nblk = gridDim.x;
  int f = blockIdx.x;
  f = (f & 7) * (nblk >> 3) + (f >> 3);   // XCD-aware swizzle (nblk % 8 == 0)
  const int txy = tx * ty;
  const int bz = f / txy;
  int r = f - bz * txy;
  const int by = r / tx;
  const int bx = r - by * tx;

  const int tid  = threadIdx.x;
  const int lane = tid & 63;
  const int wid  = tid >> 6;
  const int wr   = wid >> 2;              // 0..1 (M half)
  const int wc   = wid & 3;               // 0..3 (N quarter)
  const int lr   = lane & 15, lg = lane >> 4;

  // ---- ds_read lane bases: byte = base[kk] + imm ----
  // orig: row*128 + (((kk*4+lg)^(row&7))<<4), row = grp + lr, grp mult of 16
  //  ==>  [grpImm] + lr*128 + ((lg^(lr&3))<<4) + ((kk^((lr>>2)&1))<<6)
  const int xorlo = (lg ^ (lr & 3)) << 4;
  const int kb    = (lr >> 2) & 1;
  const int dsA0v = wr * 16384 + lr * 128 + xorlo + (kb << 6);
  const int dsA1v = wr * 16384 + lr * 128 + xorlo + ((1 ^ kb) << 6);
  const int dsB0v = 32768 + wc * 8192 + lr * 128 + xorlo + (kb << 6);
  const int dsB1v = 32768 + wc * 8192 + lr * 128 + xorlo + ((1 ^ kb) << 6);

  // ---- stage addressing: 2 advancing pointers + uniform offsets ----
  const int r7    = tid >> 3;                     // A row (alpha0,h0)
  const int pch   = tid & 7;
  const int rowB0 = (r7 & 31) | ((r7 & 32) << 1); // B row (beta0,h0)
  const long lda2 = lda * 2, ldb2 = ldb * 2;      // row stride in bytes
  const ushort_t* Abp = A + (long)bz * batchA + (long)by * 256 * lda;
  const ushort_t* Bbp = B + (long)bz * batchB + (long)bx * 256 * ldb;
  const char* gA = (const char*)(Abp + (long)r7 * lda + (pch ^ (r7 & 7)) * 8);
  const char* gB = (const char*)(Bbp + (long)rowB0 * ldb + (pch ^ (rowB0 & 7)) * 8);
  const int dA0 = r7 * 128 + pch * 16;            // LDS dest base (op A)
  const int dB0 = 32768 + rowB0 * 128 + pch * 16; // LDS dest base (op B)
  char* ldsc = (char*)&lds[0][0][0];

  // uniform per-variant source offsets (bytes): rowDelta*ld2 + tileDelta*128
  const long aP0 = 64 * lda2 + 128,  aP1 = 192 * lda2 + 128;   // alpha1 h0/h1 @t+1
  const long aP2 = 256,              aP2b = 128 * lda2 + 256;  // alpha0 h0/h1 @t+2
  const long bP0 = 32 * ldb2 + 128,  bP1 = 160 * ldb2 + 128;   // beta1  h0/h1 @t+1
  const long bP3 = 256,              bP3b = 128 * ldb2 + 256;  // beta0  h0/h1 @t+2

  f32x4 acc[8][4] = {};
  bf16x8 afr[2][2];   // current M-quarter fragments
  bf16x8 bfr[4][2];   // full-N fragments (held across the K-tile)

  auto gld = [&](const char* src, int dst) {
    __builtin_amdgcn_global_load_lds((const __attribute__((address_space(1))) void*)src,
                                     (__attribute__((address_space(3))) void*)(ldsc + dst),
                                     16, 0, 0);
  };
  auto readAq = [&](const char* lc, int q) {
#pragma unroll
    for (int mm = 0; mm < 2; ++mm) {
      afr[mm][0] = *(const bf16x8*)(lc + dsA0v + ((q * 2 + mm) << 11));
      afr[mm][1] = *(const bf16x8*)(lc + dsA1v + ((q * 2 + mm) << 11));
    }
  };
  auto readB = [&](const char* lc) {
#pragma unroll
    for (int nn = 0; nn < 4; ++nn) {
      bfr[nn][0] = *(const bf16x8*)(lc + dsB0v + (nn << 11));
      bfr[nn][1] = *(const bf16x8*)(lc + dsB1v + (nn << 11));
    }
  };
  auto mfma16q = [&](int q) {
    __builtin_amdgcn_s_setprio(1);
#pragma unroll
    for (int kk = 0; kk < 2; ++kk)
#pragma unroll
      for (int nn = 0; nn < 4; ++nn)
#pragma unroll
        for (int mm = 0; mm < 2; ++mm)
          acc[q * 2 + mm][nn] = __builtin_amdgcn_mfma_f32_16x16x32_bf16(
              afr[mm][kk], bfr[nn][kk], acc[q * 2 + mm][nn], 0, 0, 0);
    __builtin_amdgcn_s_setprio(0);
  };

  const int nkt = K >> 6;                 // >= 16 for all our shapes
  // prologue: tile0 full -> buf0 (first 8 issues), tile1 1st halves -> buf1
  gld(gA, dA0);                    gld(gA + 128 * lda2, dA0 + 16384);
  gld(gB, dB0);                    gld(gB + 128 * ldb2, dB0 + 16384);
  gld(gA + 64 * lda2, dA0 + 8192); gld(gA + 192 * lda2, dA0 + 24576);
  gld(gB + 32 * ldb2, dB0 + 4096); gld(gB + 160 * ldb2, dB0 + 20480);
  gld(gA + 128, 65536 + dA0);            gld(gA + 128 * lda2 + 128, 65536 + dA0 + 16384);
  gld(gB + 128, 65536 + dB0);            gld(gB + 128 * ldb2 + 128, 65536 + dB0 + 16384);
  WAITVM(4);                              // tile0's 8 loads landed
  BARRIER(); SCHED0();

  for (int t = 0; t < nkt - 2; ++t) {
    const int cb = t & 1;
    const char* lc = ldsc + (cb << 16);
    const int obo = (cb ^ 1) << 16, cbo = cb << 16;
    // PH0
    readAq(lc, 0); readB(lc);
    gld(gA + aP0, obo + dA0 + 8192);  gld(gB + bP0, obo + dB0 + 4096);
    mfma16q(0); BARRIER(); SCHED0();
    // PH1
    readAq(lc, 1);
    gld(gA + aP1, obo + dA0 + 24576); gld(gB + bP1, obo + dB0 + 20480);
    mfma16q(1); BARRIER(); SCHED0();
    // PH2
    readAq(lc, 2);
    gld(gA + aP2, cbo + dA0);         gld(gA + aP2b, cbo + dA0 + 16384);
    mfma16q(2); BARRIER(); SCHED0();
    // PH3
    readAq(lc, 3);
    gld(gB + bP3, cbo + dB0);         gld(gB + bP3b, cbo + dB0 + 16384);
    WAITVM(4); mfma16q(3); BARRIER(); SCHED0();
    gA += 128; gB += 128;                 // advance one K-tile (64 elem * 2B)
  }
  {                                       // t = nkt-2: stage tile nkt-1 2nd halves only
    const int cb = (nkt - 2) & 1;
    const char* lc = ldsc + (cb << 16);
    const int obo = (cb ^ 1) << 16;
    readAq(lc, 0); readB(lc);
    gld(gA + aP0, obo + dA0 + 8192);  gld(gB + bP0, obo + dB0 + 4096);
    mfma16q(0); BARRIER(); SCHED0();
    readAq(lc, 1);
    gld(gA + aP1, obo + dA0 + 24576); gld(gB + bP1, obo + dB0 + 20480);
    mfma16q(1); BARRIER(); SCHED0();
    readAq(lc, 2);
    mfma16q(2); BARRIER(); SCHED0();
    readAq(lc, 3);
    WAITVM(0);                            // drain: tile nkt-1 fully landed
    mfma16q(3); BARRIER(); SCHED0();
  }
  {                                       // t = nkt-1: pure compute, no hazards
    const int cb = (nkt - 1) & 1;
    const char* lc = ldsc + (cb << 16);
    readAq(lc, 0); readB(lc); mfma16q(0);
    readAq(lc, 1); mfma16q(1);
    readAq(lc, 2); mfma16q(2);
    readAq(lc, 3); mfma16q(3);
  }

  // epilogue: C/D frag layout col=lane&15, row=(lane>>4)*4+j
  const long Crow0 = (long)by * 256 + wr * 128;
  const long Ccol0 = (long)bx * 256 + wc * 64;
  float*     Cf = (float*)C + (long)bz * batchC;
  ushort_t*  Cb = (ushort_t*)C + (long)bz * batchC;
#pragma unroll
  for (int m = 0; m < 8; ++m) {
    long r0 = Crow0 + m * 16 + ((lane >> 4) << 2);
#pragma unroll
    for (int n = 0; n < 4; ++n) {
      long cc = Ccol0 + n * 16 + (lane & 15);
#pragma unroll
      for (int j = 0; j < 4; ++j) {
        float val = acc[m][n][j];
        if (OUT_BF16) Cb[(r0 + j) * ldc + cc] = f2bf(val);
        else          Cf[(r0 + j) * ldc + cc] = val;
      }
    }
  }
}

// ---------------------------------------------------------------------------
// row softmax over 4096 fp32 scores; write normalized P bf16 to P+row*pstride
__global__ __launch_bounds__(256) void softmax_kernel(float* __restrict__ S,
                                                      ushort_t* __restrict__ P,
                                                      long pstride) {
  float* row = S + (long)blockIdx.x * 4096;
  const int tid = threadIdx.x;
  __shared__ float red[4];

  f32x4 v[4];
#pragma unroll
  for (int i = 0; i < 4; ++i) v[i] = ((const f32x4*)row)[tid + i * 256];

  float m = -1e30f;
#pragma unroll
  for (int i = 0; i < 4; ++i)
#pragma unroll
    for (int j = 0; j < 4; ++j) m = fmaxf(m, v[i][j]);
  for (int o = 32; o; o >>= 1) m = fmaxf(m, __shfl_xor(m, o));
  if ((tid & 63) == 0) red[tid >> 6] = m;
  __syncthreads();
  m = fmaxf(fmaxf(red[0], red[1]), fmaxf(red[2], red[3]));

  float p[16];
  float s = 0.f;
#pragma unroll
  for (int i = 0; i < 4; ++i)
#pragma unroll
    for (int j = 0; j < 4; ++j) {
      float e = __expf(v[i][j] - m);
      p[i * 4 + j] = e;
      s += e;
    }
  for (int o = 32; o; o >>= 1) s += __shfl_xor(s, o);
  __syncthreads();
  if ((tid & 63) == 0) red[tid >> 6] = s;
  __syncthreads();
  s = red[0] + red[1] + red[2] + red[3];
  float inv = 1.0f / s;

  u16x4* prow = (u16x4*)(P + (long)blockIdx.x * pstride);
#pragma unroll
  for (int i = 0; i < 4; ++i) {
    u16x4 o;
    o.x = f2bf(p[i * 4 + 0] * inv);
    o.y = f2bf(p[i * 4 + 1] * inv);
    o.z = f2bf(p[i * 4 + 2] * inv);
    o.w = f2bf(p[i * 4 + 3] * inv);
    prow[tid + i * 256] = o;
  }
}

// row softmax over 4096 bf16 scores, P bf16 written IN PLACE (row-local)
__global__ __launch_bounds__(256) void softmax_bf16_kernel(ushort_t* __restrict__ S) {
  u16x4* row = (u16x4*)(S + (long)blockIdx.x * 4096);
  const int tid = threadIdx.x;
  __shared__ float red[4];

  float v[16];
#pragma unroll
  for (int i = 0; i < 4; ++i) {
    u16x4 h = row[tid + i * 256];
    v[i * 4 + 0] = bf2f(h.x); v[i * 4 + 1] = bf2f(h.y);
    v[i * 4 + 2] = bf2f(h.z); v[i * 4 + 3] = bf2f(h.w);
  }

  float m = -1e30f;
#pragma unroll
  for (int i = 0; i < 16; ++i) m = fmaxf(m, v[i]);
  for (int o = 32; o; o >>= 1) m = fmaxf(m, __shfl_xor(m, o));
  if ((tid & 63) == 0) red[tid >> 6] = m;
  __syncthreads();
  m = fmaxf(fmaxf(red[0], red[1]), fmaxf(red[2], red[3]));

  float s = 0.f;
#pragma unroll
  for (int i = 0; i < 16; ++i) {
    v[i] = __expf(v[i] - m);
    s += v[i];
  }
  for (int o = 32; o; o >>= 1) s += __shfl_xor(s, o);
  __syncthreads();
  if ((tid & 63) == 0) red[tid >> 6] = s;
  __syncthreads();
  s = red[0] + red[1] + red[2] + red[3];
  float inv = 1.0f / s;

#pragma unroll
  for (int i = 0; i < 4; ++i) {
    u16x4 o;
    o.x = f2bf(v[i * 4 + 0] * inv);
    o.y = f2bf(v[i * 4 + 1] * inv);
    o.z = f2bf(v[i * 4 + 2] * inv);
    o.w = f2bf(v[i * 4 + 3] * inv);
    row[tid + i * 256] = o;
  }
}

// ---------------------------------------------------------------------------
extern "C" void kernel_launch(void* const* d_in, const int* in_sizes, int n_in,
                              void* d_out, int out_size, void* d_ws, size_t ws_size,
                              hipStream_t stream) {
  const float* x    = (const float*)d_in[0];   // [4,4096,1024]
  const float* kern = (const float*)d_in[1];   // [3,1024,1024]
  float* out = (float*)d_out;                  // [4,4096,1024]

  char* p = (char*)d_ws;
  ushort_t* xbf = (ushort_t*)p; p += 33554432;         // 16384x1024 bf16
  ushort_t* t   = (ushort_t*)p; p += 33554432;         // 16384x1024 bf16
  ushort_t* vT  = (ushort_t*)p; p += 33554432;         // 4x1024x4096 bf16
  ushort_t* wk  = (ushort_t*)p; p += 2097152;
  ushort_t* wq  = (ushort_t*)p; p += 2097152;
  ushort_t* wvt = (ushort_t*)p; p += 2097152;
  ushort_t* mt  = (ushort_t*)p; p += 2097152;
  size_t fixed = (size_t)(p - (char*)d_ws);            // 104 MiB

  cast_bf16_kernel<<<8192, 256, 0, stream>>>(x, xbf);
  prep_weights_kernel<<<4096, 256, 0, stream>>>(kern, wk, wq, wvt);
  // Mt[d',d] = sum_e Wk[d',e] * Wq_s[d,e]  (tiny; 128^2 kernel)
  gemm_bt<1><<<dim3(8, 8, 1), 256, 0, stream>>>(wk, 1024, 0, wq, 1024, 0, mt, 1024, 0, 1024);

  const size_t need4 = fixed + 4ull * 33554432;        // 4 bf16 S/P buffers
  const size_t need2 = fixed + 2ull * 33554432;        // 2 bf16 S/P buffers

  if (ws_size >= need2) {
    ushort_t* Sb = (ushort_t*)p;                       // 2 or 4 x (4096x4096 bf16)

    // t[q,d'] = sum_d x[q,d] * Mt[d',d]      grid 4x64 = 256
    gemm256<1><<<dim3(256), dim3(512), 0, stream>>>(xbf, 1024, 0, mt, 1024, 0,
                                                    t, 1024, 0, 1024, 4, 64);
    // vT[b][e,s] = sum_d WvT[e,d] * x_b[s,d]  grid 16x4x4 = 256
    gemm256<1><<<dim3(256), dim3(512), 0, stream>>>(wvt, 1024, 0,
                                                    xbf, 1024, 4194304,
                                                    vT, 4096, 4194304, 1024, 16, 4);

    const int nb_at_once = (ws_size >= need4) ? 4 : 2;
    for (int b0 = 0; b0 < 4; b0 += nb_at_once) {
      // S_b[q,k] = sum_d' t_b[q,d'] x_b[k,d']  (bf16 out), batched dispatch
      gemm256<1><<<dim3(256 * nb_at_once), dim3(512), 0, stream>>>(
          t + (long)b0 * 4194304, 1024, 4194304,
          xbf + (long)b0 * 4194304, 1024, 4194304,
          Sb, 4096, 16777216, 1024, 16, 16);
      // softmax all staged rows in one dispatch (in-place bf16 P)
      softmax_bf16_kernel<<<4096 * nb_at_once, 256, 0, stream>>>(Sb);
      // out[b][q,e] = sum_k P_b[q,k] vT_b[e,k]
      gemm256<0><<<dim3(4 * 16 * nb_at_once), dim3(512), 0, stream>>>(
          Sb, 4096, 16777216,
          vT + (long)b0 * 4194304, 4096, 4194304,
          out + (long)b0 * 4194304, 1024, 4194304, 4096, 4, 16);
    }
  } else {
    // -------- low-ws fallback (chunked, in-place packed P) --------
    float* Sbuf = (float*)p;
    long CR = 4096;
    while (CR > 256 && fixed + (size_t)CR * 4096 * 4 > ws_size) CR >>= 1;

    gemm_bt<1><<<dim3(8, 128, 1), 256, 0, stream>>>(xbf, 1024, 0, mt, 1024, 0, t, 1024, 0, 1024);
    gemm_bt<1><<<dim3(32, 8, 4), 256, 0, stream>>>(wvt, 1024, 0,
                                                   xbf, 1024, 4194304,
                                                   vT, 4096, 4194304, 1024);
    for (int b = 0; b < 4; ++b) {
      const ushort_t* xb  = xbf + (long)b * 4194304;
      const ushort_t* vTb = vT  + (long)b * 4194304;
      for (long c0 = 0; c0 < 4096; c0 += CR) {
        const ushort_t* tb = t + ((long)b * 4096 + c0) * 1024;
        gemm_bt<0><<<dim3(32, CR / 128, 1), 256, 0, stream>>>(tb, 1024, 0, xb, 1024, 0,
                                                              Sbuf, 4096, 0, 1024);
        softmax_kernel<<<CR, 256, 0, stream>>>(Sbuf, (ushort_t*)Sbuf, 8192);
        gemm_bt<0><<<dim3(8, CR / 128, 1), 256, 0, stream>>>((const ushort_t*)Sbuf, 8192, 0,
                                                             vTb, 4096, 0,
                                                             out + ((long)b * 4096 + c0) * 1024, 1024, 0,
                                                             4096);
      }
    }
  }
}